// Round 7
// baseline (368.116 us; speedup 1.0000x reference)
//
#include <hip/hip_runtime.h>
#include <math.h>

#define NHEADS 16
#define HD 64
#define MMEM 16384
#define NQ 1024   // B*S per head
#define SEQ 512
#define EPS 1e-8f
#define NPART 8
#define NTILES 64    // 32-mem tiles per partition (16384/8/32)
#define CHTILES 16   // tiles per staged chunk (64 KB)
#define NCHUNK 4
#define CMAX 16      // candidate slots per (query, partition, lane-half)
#define DKEY 512u    // keep-set margin in key units (~0.2 raw-dot)

typedef short bf16x8 __attribute__((ext_vector_type(8)));
typedef float f32x16 __attribute__((ext_vector_type(16)));

typedef const __attribute__((address_space(1))) unsigned int* gas_u32p;
typedef __attribute__((address_space(3))) unsigned int* las_u32p;

__device__ inline unsigned short f2bf(float f) {
    unsigned int u = __builtin_bit_cast(unsigned int, f);
    unsigned int r = (u + 0x7FFFu + ((u >> 16) & 1u)) >> 16;  // RNE
    return (unsigned short)r;
}

// ---------------------------------------------------------------------------
// Kernel 1: reciprocal L2 norm per key-memory row.
// ---------------------------------------------------------------------------
__global__ void knorm_kernel(const float* __restrict__ kmem,
                             float* __restrict__ knr) {
    int gid = blockIdx.x * 256 + threadIdx.x;
    int mem = gid >> 4;
    int d4  = gid & 15;
    float4 kv = reinterpret_cast<const float4*>(kmem)[(size_t)mem * 16 + d4];
    float ss = kv.x * kv.x + kv.y * kv.y + kv.z * kv.z + kv.w * kv.w;
    ss += __shfl_xor(ss, 1);
    ss += __shfl_xor(ss, 2);
    ss += __shfl_xor(ss, 4);
    ss += __shfl_xor(ss, 8);
    if (d4 == 0) knr[mem] = 1.0f / fmaxf(sqrtf(ss), EPS);
}

// ---------------------------------------------------------------------------
// Kernel 2: normalized bf16 keys in MFMA-A-fragment tile order.
// Tile = 32 mems x 64 d. Byte layout: (((h*512+t)*4+ks)*64+lane)*16 + j*2
// holds kmem[h][t*32+(lane&31)][ks*16+(lane>>5)*8+j] * knr (bf16).
// ---------------------------------------------------------------------------
__global__ __launch_bounds__(256)
void kprep_kernel(const float* __restrict__ kmem,
                  const float* __restrict__ knr,
                  unsigned short* __restrict__ kbf) {
    int gid = blockIdx.x * 256 + threadIdx.x;
    int lane = gid & 63;
    int ks   = (gid >> 6) & 3;
    int t    = (gid >> 8) & 511;
    int h    = gid >> 17;
    int row  = t * 32 + (lane & 31);
    int d0   = ks * 16 + ((lane >> 5) << 3);
    const float* src = kmem + (((size_t)h * MMEM + row) << 6) + d0;
    float sc = knr[h * MMEM + row];
    float4 v0 = *(const float4*)(src);
    float4 v1 = *(const float4*)(src + 4);
    uint4 o;
    o.x = (unsigned)f2bf(v0.x * sc) | ((unsigned)f2bf(v0.y * sc) << 16);
    o.y = (unsigned)f2bf(v0.z * sc) | ((unsigned)f2bf(v0.w * sc) << 16);
    o.z = (unsigned)f2bf(v1.x * sc) | ((unsigned)f2bf(v1.y * sc) << 16);
    o.w = (unsigned)f2bf(v1.z * sc) | ((unsigned)f2bf(v1.w * sc) << 16);
    *(uint4*)(kbf + (size_t)gid * 8) = o;
}

// ---------------------------------------------------------------------------
// Kernel 3: LDS-resident two-pass threshold MFMA scan.
// Grid (h=16, qhalf=2, p=8) = 256 blocks x 512 thr (8 waves); LDS = 2x64 KB
// double-buffered chunks of 16 tiles; each wave handles 2 query-groups
// (64 queries), so a staged tile serves 512 queries -> global scan traffic
// = 2 passes x 33.5 MB x 2 qhalf = 134 MB total.
// Pass 1: tau = 8th-largest per-tile max (branchless ins8; superset proof:
//   >=8 tile-maxes > v8 would mean >=8 values > v8, contradiction).
// Pass 2: emit packed (key16<<16|mem_idx) for values >= tau; key is a
//   monotone 16-bit quantization of fma(acc,0.125,2.0) bit-pattern
//   (valid: emitted values >= tau > 0 -> domain [2,3.5) -> 16-bit key).
// D-layout: col=lane&31 (query), row=(reg&3)+8*(reg>>2)+4*(lane>>5) (mem).
// ---------------------------------------------------------------------------
#define MAX16(ACC)                                                            \
    fmaxf(fmaxf(fmaxf(fmaxf(ACC[0],ACC[1]),fmaxf(ACC[2],ACC[3])),             \
                fmaxf(fmaxf(ACC[4],ACC[5]),fmaxf(ACC[6],ACC[7]))),            \
          fmaxf(fmaxf(fmaxf(ACC[8],ACC[9]),fmaxf(ACC[10],ACC[11])),           \
                fmaxf(fmaxf(ACC[12],ACC[13]),fmaxf(ACC[14],ACC[15]))))

__device__ inline void ins8(float (&tv)[8], float v) {
#pragma unroll
    for (int j = 0; j < 8; ++j) {
        float h_ = fmaxf(tv[j], v);
        float l_ = fminf(tv[j], v);
        tv[j] = h_;
        v = l_;
    }
}

__device__ inline void ins8u(unsigned (&tv)[8], unsigned v) {
#pragma unroll
    for (int j = 0; j < 8; ++j) {
        unsigned h_ = tv[j] > v ? tv[j] : v;
        unsigned l_ = tv[j] > v ? v : tv[j];
        tv[j] = h_;
        v = l_;
    }
}

#define EMITP(ACC, TAU, C, LST, MBV) do {                                     \
    _Pragma("unroll")                                                         \
    for (int _r = 0; _r < 16; ++_r) {                                         \
        if (ACC[_r] >= (TAU)) {                                               \
            unsigned _key = (__builtin_bit_cast(unsigned,                     \
                fmaf(ACC[_r], 0.125f, 2.0f)) - 0x3F800000u) >> 8;             \
            unsigned _e = ((_key << 16) | (unsigned)(MBV))                    \
                          + (unsigned)((_r & 3) + 8 * (_r >> 2));             \
            if ((C) < CMAX) (LST)[C] = _e;                                    \
            ++(C);                                                            \
        }                                                                     \
    }                                                                         \
} while (0)

__device__ inline bf16x8 pack8(const float* p) {
    float4 a = *(const float4*)p;
    float4 b = *(const float4*)(p + 4);
    bf16x8 f;
    f[0] = (short)f2bf(a.x); f[1] = (short)f2bf(a.y);
    f[2] = (short)f2bf(a.z); f[3] = (short)f2bf(a.w);
    f[4] = (short)f2bf(b.x); f[5] = (short)f2bf(b.y);
    f[6] = (short)f2bf(b.z); f[7] = (short)f2bf(b.w);
    return f;
}

__global__ __launch_bounds__(512, 2)
void scan_mfma_kernel(const float* __restrict__ query,
                      const unsigned short* __restrict__ kbf,
                      unsigned int* __restrict__ pcand,
                      unsigned int* __restrict__ pcnt) {
    __shared__ __align__(16) unsigned char lds[2][65536];
    const int tid  = threadIdx.x;
    const int lane = tid & 63;
    const int wid  = tid >> 6;
    int bid = blockIdx.x;
    const int p  = bid & 7;  bid >>= 3;
    const int qh = bid & 1;  bid >>= 1;
    const int h  = bid;
    const int col = lane & 31;
    const int hi  = lane >> 5;
    const int n0  = qh * 512 + wid * 64 + col;  // query group A
    const int n1  = n0 + 32;                    // query group B

    // B fragments (raw queries; per-query scale doesn't change ranking)
    bf16x8 qA[4], qB[4];
    {
        const int b0 = n0 >> 9, s0 = n0 & 511;
        const int b1 = n1 >> 9, s1 = n1 & 511;
        const float* qp0 = query + ((((size_t)b0 * NHEADS + h) * SEQ + s0) << 6);
        const float* qp1 = query + ((((size_t)b1 * NHEADS + h) * SEQ + s1) << 6);
#pragma unroll
        for (int ks = 0; ks < 4; ++ks) {
            qA[ks] = pack8(qp0 + ks * 16 + hi * 8);
            qB[ks] = pack8(qp1 + ks * 16 + hi * 8);
        }
    }

    const unsigned char* gsrc = (const unsigned char*)kbf
        + ((size_t)h * 512 + (size_t)p * NTILES) * 4096;

#define STAGE(CH) do {                                                        \
        const unsigned char* _s = gsrc + (size_t)(CH) * 65536;                \
        unsigned char* _d = &lds[(CH) & 1][0];                                \
        _Pragma("unroll")                                                     \
        for (int _j = 0; _j < 8; ++_j)                                        \
            __builtin_amdgcn_global_load_lds(                                 \
                (gas_u32p)(const void*)(_s + _j * 8192 + tid * 16),           \
                (las_u32p)(void*)(_d + _j * 8192 + tid * 16), 16, 0, 0);      \
    } while (0)

    // ---------------- pass 1: tau per query-group ----------------
    float tvA[8], tvB[8];
#pragma unroll
    for (int j = 0; j < 8; ++j) { tvA[j] = -1e30f; tvB[j] = -1e30f; }

    STAGE(0);
    __syncthreads();
    for (int c = 0; c < NCHUNK; ++c) {
        if (c + 1 < NCHUNK) STAGE(c + 1);
        const unsigned char* base = &lds[c & 1][0];
#pragma unroll 1
        for (int t = 0; t < CHTILES; ++t) {
            const unsigned char* tb = base + t * 4096 + lane * 16;
            bf16x8 a0 = *(const bf16x8*)(tb);
            bf16x8 a1 = *(const bf16x8*)(tb + 1024);
            bf16x8 a2 = *(const bf16x8*)(tb + 2048);
            bf16x8 a3 = *(const bf16x8*)(tb + 3072);
            f32x16 accA = {0,0,0,0,0,0,0,0,0,0,0,0,0,0,0,0};
            f32x16 accB = {0,0,0,0,0,0,0,0,0,0,0,0,0,0,0,0};
            accA = __builtin_amdgcn_mfma_f32_32x32x16_bf16(a0, qA[0], accA, 0, 0, 0);
            accB = __builtin_amdgcn_mfma_f32_32x32x16_bf16(a0, qB[0], accB, 0, 0, 0);
            accA = __builtin_amdgcn_mfma_f32_32x32x16_bf16(a1, qA[1], accA, 0, 0, 0);
            accB = __builtin_amdgcn_mfma_f32_32x32x16_bf16(a1, qB[1], accB, 0, 0, 0);
            accA = __builtin_amdgcn_mfma_f32_32x32x16_bf16(a2, qA[2], accA, 0, 0, 0);
            accB = __builtin_amdgcn_mfma_f32_32x32x16_bf16(a2, qB[2], accB, 0, 0, 0);
            accA = __builtin_amdgcn_mfma_f32_32x32x16_bf16(a3, qA[3], accA, 0, 0, 0);
            accB = __builtin_amdgcn_mfma_f32_32x32x16_bf16(a3, qB[3], accB, 0, 0, 0);
            ins8(tvA, MAX16(accA));
            ins8(tvB, MAX16(accB));
        }
        __syncthreads();
    }
    const float tauA = tvA[7];
    const float tauB = tvB[7];

    // ---------------- pass 2: emit packed candidates >= tau ----------------
    unsigned int cA = 0, cB = 0;
    const size_t chA = (((size_t)h * NQ + n0) * NPART + p) * 2 + hi;
    const size_t chB = (((size_t)h * NQ + n1) * NPART + p) * 2 + hi;
    unsigned int* mA = pcand + chA * CMAX;
    unsigned int* mB = pcand + chB * CMAX;

    STAGE(0);
    __syncthreads();
    for (int c = 0; c < NCHUNK; ++c) {
        if (c + 1 < NCHUNK) STAGE(c + 1);
        const unsigned char* base = &lds[c & 1][0];
#pragma unroll 1
        for (int t = 0; t < CHTILES; ++t) {
            const unsigned char* tb = base + t * 4096 + lane * 16;
            bf16x8 a0 = *(const bf16x8*)(tb);
            bf16x8 a1 = *(const bf16x8*)(tb + 1024);
            bf16x8 a2 = *(const bf16x8*)(tb + 2048);
            bf16x8 a3 = *(const bf16x8*)(tb + 3072);
            f32x16 accA = {0,0,0,0,0,0,0,0,0,0,0,0,0,0,0,0};
            f32x16 accB = {0,0,0,0,0,0,0,0,0,0,0,0,0,0,0,0};
            accA = __builtin_amdgcn_mfma_f32_32x32x16_bf16(a0, qA[0], accA, 0, 0, 0);
            accB = __builtin_amdgcn_mfma_f32_32x32x16_bf16(a0, qB[0], accB, 0, 0, 0);
            accA = __builtin_amdgcn_mfma_f32_32x32x16_bf16(a1, qA[1], accA, 0, 0, 0);
            accB = __builtin_amdgcn_mfma_f32_32x32x16_bf16(a1, qB[1], accB, 0, 0, 0);
            accA = __builtin_amdgcn_mfma_f32_32x32x16_bf16(a2, qA[2], accA, 0, 0, 0);
            accB = __builtin_amdgcn_mfma_f32_32x32x16_bf16(a2, qB[2], accB, 0, 0, 0);
            accA = __builtin_amdgcn_mfma_f32_32x32x16_bf16(a3, qA[3], accA, 0, 0, 0);
            accB = __builtin_amdgcn_mfma_f32_32x32x16_bf16(a3, qB[3], accB, 0, 0, 0);
            const int mbv = p * 2048 + (c * CHTILES + t) * 32 + 4 * hi;
            EMITP(accA, tauA, cA, mA, mbv);
            EMITP(accB, tauB, cB, mB, mbv);
        }
        __syncthreads();
    }
    pcnt[chA] = cA;
    pcnt[chB] = cB;
#undef STAGE
}

// ---------------------------------------------------------------------------
// Kernel 4: keep-set pre-filter + exact fp32 rescore.
// Stream the <=32 packed entries twice: (a) t8b = 8th-largest key (ins8u),
// (b) fp32-rescore only entries with key >= t8b - DKEY (superset of the
// fp32 top-8: |bf16score - fp32score| <= 2^-8*||q|| raw; DKEY=512 key units
// ~= 0.2 raw >= 6x that bound). Per-partition top-8, (desc, idx asc) ties.
// Overflowed halves fall back to an exact full-partition fp32 scan.
// ---------------------------------------------------------------------------
#define KROW(I, Q) kv = kp[I]; \
    a0 = fmaf(Q.x, kv.x, a0); a1 = fmaf(Q.y, kv.y, a1); \
    a2 = fmaf(Q.z, kv.z, a2); a3 = fmaf(Q.w, kv.w, a3);
#define SS(Q) (Q.x*Q.x + Q.y*Q.y + Q.z*Q.z + Q.w*Q.w)
#define DOT64()                                                  \
    float a0 = 0.f, a1 = 0.f, a2 = 0.f, a3 = 0.f;                \
    float4 kv;                                                   \
    KROW(0, q0)  KROW(1, q1)  KROW(2, q2)  KROW(3, q3)           \
    KROW(4, q4)  KROW(5, q5)  KROW(6, q6)  KROW(7, q7)           \
    KROW(8, q8)  KROW(9, q9)  KROW(10, q10) KROW(11, q11)        \
    KROW(12, q12) KROW(13, q13) KROW(14, q14) KROW(15, q15)
#define TINS(SC, IDX)                                                         \
    if ((SC) > tv[7] || ((SC) == tv[7] && (IDX) < ti[7])) {                   \
        tv[7] = (SC); ti[7] = (IDX);                                          \
        _Pragma("unroll")                                                     \
        for (int _j = 7; _j > 0; --_j) {                                      \
            bool _sw = (tv[_j] > tv[_j-1]) ||                                 \
                       (tv[_j] == tv[_j-1] && ti[_j] < ti[_j-1]);             \
            if (_sw) {                                                        \
                float _tf = tv[_j]; tv[_j] = tv[_j-1]; tv[_j-1] = _tf;        \
                int   _tu = ti[_j]; ti[_j] = ti[_j-1]; ti[_j-1] = _tu;        \
            }                                                                 \
        }                                                                     \
    }

__global__ __launch_bounds__(256, 4)
void rescore_kernel(const float* __restrict__ query,
                    const float* __restrict__ kmem,
                    const float* __restrict__ knr,
                    const unsigned int* __restrict__ pcand,
                    const unsigned int* __restrict__ pcnt,
                    float* __restrict__ pscore,
                    int* __restrict__ pidx) {
    int gid = blockIdx.x * 256 + threadIdx.x;  // (h, q, p)
    int p = gid & 7;
    int n = (gid >> 3) & 1023;
    int h = gid >> 13;
    int b = n >> 9, s = n & 511;
    const float4* qv = (const float4*)(query + ((((size_t)b * NHEADS + h) * SEQ + s) << 6));
    float4 q0 = qv[0],  q1 = qv[1],  q2 = qv[2],  q3 = qv[3];
    float4 q4 = qv[4],  q5 = qv[5],  q6 = qv[6],  q7 = qv[7];
    float4 q8 = qv[8],  q9 = qv[9],  q10 = qv[10], q11 = qv[11];
    float4 q12 = qv[12], q13 = qv[13], q14 = qv[14], q15 = qv[15];
    float ss = SS(q0)+SS(q1)+SS(q2)+SS(q3)+SS(q4)+SS(q5)+SS(q6)+SS(q7)
             + SS(q8)+SS(q9)+SS(q10)+SS(q11)+SS(q12)+SS(q13)+SS(q14)+SS(q15);
    const float qs = 1.0f / (fmaxf(sqrtf(ss), EPS) * 8.0f);

    float tv[8]; int ti[8];
#pragma unroll
    for (int j = 0; j < 8; ++j) { tv[j] = -1e30f; ti[j] = 0x7fffffff; }

    const size_t ch = (((size_t)h * NQ + n) * NPART + p) * 2;
    const unsigned int c0 = pcnt[ch], c1 = pcnt[ch + 1];
    const float* kb = kmem + ((size_t)h << 20);
    const float* nb = knr + h * MMEM;

    if (c0 > CMAX || c1 > CMAX) {
        // exact fallback: full fp32 scan of the partition (near-never)
        const int m0 = p * (MMEM / NPART);
#pragma unroll 1
        for (int m = m0; m < m0 + MMEM / NPART; ++m) {
            const float4* kp = (const float4*)(kb + ((size_t)m << 6));
            DOT64()
            const float sc = ((a0 + a1) + (a2 + a3)) * qs * nb[m];
            TINS(sc, m)
        }
    } else {
        const unsigned int* l0 = pcand + ch * CMAX;
        const unsigned int* l1 = pcand + (ch + 1) * CMAX;
        const unsigned int ct = c0 + c1;

        // pass A: 8th-largest packed key
        unsigned tvk[8];
#pragma unroll
        for (int j = 0; j < 8; ++j) tvk[j] = 0u;
#pragma unroll 1
        for (unsigned int c = 0; c < ct; ++c) {
            unsigned int e = (c < c0) ? l0[c] : l1[c - c0];
            ins8u(tvk, e);
        }
        unsigned int cut = tvk[7] >> 16;
        cut = (cut > DKEY) ? cut - DKEY : 0u;

        // pass B: fp32-rescore the keep-set
#pragma unroll 1
        for (unsigned int c = 0; c < ct; ++c) {
            unsigned int e = (c < c0) ? l0[c] : l1[c - c0];
            if ((e >> 16) < cut) continue;
            const int idx = (int)(e & 0xFFFFu);
            const float4* kp = (const float4*)(kb + ((size_t)idx << 6));
            DOT64()
            const float sc = ((a0 + a1) + (a2 + a3)) * qs * nb[idx];
            TINS(sc, idx)
        }
    }

    const size_t ob = (((size_t)h * NQ + n) * NPART + p) * 8;
#pragma unroll
    for (int j = 0; j < 8; ++j) { pscore[ob + j] = tv[j]; pidx[ob + j] = ti[j]; }
}

// ---------------------------------------------------------------------------
// Kernel 5: merge partial top-8 lists (fp32-exact, tie-safe: lists are
// (score desc, idx asc) and partitions ascend in index), gather values,
// sigmoid-gate blend.
// ---------------------------------------------------------------------------
__global__ void merge_kernel(const float* __restrict__ pscore,
                             const int* __restrict__ pidx,
                             const float* __restrict__ vmem,
                             const float* __restrict__ outputs,
                             const float* __restrict__ gate,
                             float* __restrict__ out, int P) {
    const int t = blockIdx.x * 256 + threadIdx.x;
    const int h = t >> 10;
    const int n = t & 1023;
    const int b = n >> 9;
    const int s = n & 511;

    float tv[8]; int ti[8];
    const size_t base = ((size_t)h * NQ + n) * P * 8;
#pragma unroll
    for (int j = 0; j < 8; ++j) { tv[j] = pscore[base + j]; ti[j] = pidx[base + j]; }
    const int total = P * 8;
    for (int c = 8; c < total; ++c) {
        const float v = pscore[base + c];
        if (v > tv[7]) {
            tv[7] = v; ti[7] = pidx[base + c];
#pragma unroll
            for (int j = 7; j > 0; --j) {
                if (tv[j] > tv[j-1]) {
                    float tf = tv[j]; tv[j] = tv[j-1]; tv[j-1] = tf;
                    int   tu = ti[j]; ti[j] = ti[j-1]; ti[j-1] = tu;
                }
            }
        }
    }

    float4 acc[16];
#pragma unroll
    for (int i = 0; i < 16; ++i) acc[i] = make_float4(0.f, 0.f, 0.f, 0.f);
#pragma unroll
    for (int j = 0; j < 8; ++j) {
        const float4* vp = reinterpret_cast<const float4*>(
            vmem + ((size_t)h * MMEM + ti[j]) * HD);
        const float sc = tv[j];
#pragma unroll
        for (int i = 0; i < 16; ++i) {
            float4 v = vp[i];
            acc[i].x = fmaf(sc, v.x, acc[i].x);
            acc[i].y = fmaf(sc, v.y, acc[i].y);
            acc[i].z = fmaf(sc, v.z, acc[i].z);
            acc[i].w = fmaf(sc, v.w, acc[i].w);
        }
    }

    const float g  = 1.0f / (1.0f + expf(-gate[h]));
    const float og = 1.0f - g;
    const size_t off = (((size_t)b * NHEADS + h) * SEQ + s) * HD;
    const float4* op = reinterpret_cast<const float4*>(outputs + off);
    float4* dst = reinterpret_cast<float4*>(out + off);
#pragma unroll
    for (int i = 0; i < 16; ++i) {
        float4 o = op[i];
        float4 r;
        r.x = g * acc[i].x + og * o.x;
        r.y = g * acc[i].y + og * o.y;
        r.z = g * acc[i].z + og * o.z;
        r.w = g * acc[i].w + og * o.w;
        dst[i] = r;
    }
}

// ---------------------------------------------------------------------------
// Fallback fp32 scan, used only if ws is too small for the MFMA path.
// ---------------------------------------------------------------------------
__global__ __launch_bounds__(64, 4)
void scan_kernel(const float* __restrict__ query,
                 const float* __restrict__ kmem,
                 const float* __restrict__ knr,
                 float* __restrict__ pscore,
                 int* __restrict__ pidx,
                 int P, int CH) {
    const int lane = threadIdx.x & 63;
    int bid = blockIdx.x;
    const int p  = bid % P;  bid /= P;
    const int qb = bid & 15; bid >>= 4;
    const int h  = bid;
    const int n  = qb * 64 + lane;
    const int b  = n >> 9;
    const int s  = n & 511;

    const float4* qp = reinterpret_cast<const float4*>(
        query + (((size_t)b * NHEADS + h) * SEQ + s) * HD);
    float q[HD];
    float ss = 0.0f;
#pragma unroll
    for (int i = 0; i < 16; ++i) {
        float4 v = qp[i];
        q[4*i+0] = v.x; q[4*i+1] = v.y; q[4*i+2] = v.z; q[4*i+3] = v.w;
        ss += v.x * v.x + v.y * v.y + v.z * v.z + v.w * v.w;
    }
    const float rq = 1.0f / (fmaxf(sqrtf(ss), EPS) * 8.0f);
#pragma unroll
    for (int i = 0; i < HD; ++i) q[i] *= rq;

    float tv[8]; int ti[8];
#pragma unroll
    for (int j = 0; j < 8; ++j) { tv[j] = -INFINITY; ti[j] = 0; }

    const int m0 = p * CH;
    const float4* kp = reinterpret_cast<const float4*>(
        kmem + ((size_t)h * MMEM + m0) * HD);
    const float* knrp = knr + h * MMEM + m0;

    for (int mm = 0; mm < CH; ++mm) {
        float d0 = 0.f, d1 = 0.f, d2 = 0.f, d3 = 0.f;
#pragma unroll
        for (int i = 0; i < 16; ++i) {
            float4 kv = kp[(size_t)mm * 16 + i];
            d0 = fmaf(q[4*i+0], kv.x, d0);
            d1 = fmaf(q[4*i+1], kv.y, d1);
            d2 = fmaf(q[4*i+2], kv.z, d2);
            d3 = fmaf(q[4*i+3], kv.w, d3);
        }
        const float sim = ((d0 + d1) + (d2 + d3)) * knrp[mm];
        if (sim > tv[7]) {
            tv[7] = sim; ti[7] = m0 + mm;
#pragma unroll
            for (int j = 7; j > 0; --j) {
                if (tv[j] > tv[j-1]) {
                    float tf = tv[j]; tv[j] = tv[j-1]; tv[j-1] = tf;
                    int   tu = ti[j]; ti[j] = ti[j-1]; ti[j-1] = tu;
                }
            }
        }
    }

    const size_t base = (((size_t)h * NQ + n) * P + p) * 8;
#pragma unroll
    for (int j = 0; j < 8; ++j) { pscore[base+j] = tv[j]; pidx[base+j] = ti[j]; }
}

// ---------------------------------------------------------------------------
extern "C" void kernel_launch(void* const* d_in, const int* in_sizes, int n_in,
                              void* d_out, int out_size, void* d_ws, size_t ws_size,
                              hipStream_t stream) {
    const float* query   = (const float*)d_in[1];
    const float* outputs = (const float*)d_in[4];
    const float* gate    = (const float*)d_in[5];
    const float* kmem    = (const float*)d_in[6];
    const float* vmem    = (const float*)d_in[7];
    float* out = (float*)d_out;

    const size_t sz_knr   = (size_t)NHEADS * MMEM * 4;                   //  1.0 MB
    const size_t sz_kbf   = (size_t)NHEADS * MMEM * HD * 2;              // 33.5 MB
    const size_t sz_pcand = (size_t)NHEADS * NQ * NPART * 2 * CMAX * 4;  // 16.8 MB
    const size_t sz_pcnt  = (size_t)NHEADS * NQ * NPART * 2 * 4;         //  1.0 MB
    const size_t sz_plist = (size_t)NHEADS * NQ * NPART * 8 * 4;         //  4.2 MB
    const size_t need = sz_knr + sz_kbf + sz_pcand + sz_pcnt + 2 * sz_plist;

    if (ws_size >= need) {
        char* w = (char*)d_ws;
        float*          knr     = (float*)w;          w += sz_knr;
        unsigned short* kbf     = (unsigned short*)w; w += sz_kbf;
        unsigned int*   pcand   = (unsigned int*)w;   w += sz_pcand;
        unsigned int*   pcnt    = (unsigned int*)w;   w += sz_pcnt;
        float*          pscore2 = (float*)w;          w += sz_plist;
        int*            pidx2   = (int*)w;

        knorm_kernel<<<(NHEADS * MMEM * 16) / 256, 256, 0, stream>>>(kmem, knr);
        kprep_kernel<<<(NHEADS * 512 * 4 * 64) / 256, 256, 0, stream>>>(kmem, knr, kbf);
        scan_mfma_kernel<<<NHEADS * 2 * NPART, 512, 0, stream>>>(query, kbf, pcand, pcnt);
        rescore_kernel<<<(NHEADS * NQ * NPART) / 256, 256, 0, stream>>>(
            query, kmem, knr, pcand, pcnt, pscore2, pidx2);
        merge_kernel<<<(NHEADS * NQ) / 256, 256, 0, stream>>>(
            pscore2, pidx2, vmem, outputs, gate, out, NPART);
    } else {
        int P = 16;
        while (P > 4 &&
               (size_t)NHEADS * MMEM * 4 + (size_t)NHEADS * NQ * (size_t)P * 64 > ws_size)
            P >>= 1;
        const int CH = MMEM / P;

        float* knr    = (float*)d_ws;
        float* pscore = knr + (size_t)NHEADS * MMEM;
        int*   pidx   = (int*)(pscore + (size_t)NHEADS * NQ * (size_t)P * 8);

        knorm_kernel<<<(NHEADS * MMEM * 16) / 256, 256, 0, stream>>>(kmem, knr);
        scan_kernel<<<NHEADS * 16 * P, 64, 0, stream>>>(
            query, kmem, knr, pscore, pidx, P, CH);
        merge_kernel<<<(NHEADS * NQ) / 256, 256, 0, stream>>>(
            pscore, pidx, vmem, outputs, gate, out, P);
    }
}

// Round 8
// 287.403 us; speedup vs baseline: 1.2808x; 1.2808x over previous
//
#include <hip/hip_runtime.h>
#include <math.h>

#define NHEADS 16
#define HD 64
#define MMEM 16384
#define NQ 1024   // B*S per head
#define SEQ 512
#define EPS 1e-8f
#define NPART 8
#define NT 64     // 32-mem tiles per partition
#define CMAX 16   // candidate slots per (query, partition, lane-half)

typedef short bf16x8 __attribute__((ext_vector_type(8)));
typedef float f32x16 __attribute__((ext_vector_type(16)));

__device__ inline unsigned short f2bf(float f) {
    unsigned int u = __builtin_bit_cast(unsigned int, f);
    unsigned int r = (u + 0x7FFFu + ((u >> 16) & 1u)) >> 16;  // RNE
    return (unsigned short)r;
}

// monotone 16-bit key for raw bf16-dot v (domain clamped to [-8, ~16))
__device__ inline unsigned vkey(float v) {
    float f = fmaf(v, 0.125f, 2.0f);
    f = fminf(fmaxf(f, 1.0f), 3.9999998f);
    return (__builtin_bit_cast(unsigned, f) - 0x3F800000u) >> 8;
}
__device__ inline float vunkey(unsigned k) {
    float f = __builtin_bit_cast(float, (k << 8) + 0x3F800000u);
    return (f - 2.0f) * 8.0f;
}

#define SS(Q) (Q.x*Q.x + Q.y*Q.y + Q.z*Q.z + Q.w*Q.w)

// ---------------------------------------------------------------------------
// Kernel 1: fused knorm + kprep. Block = one (h, tile): 32 rows x 64 d.
// Row 1/||k|| via LDS reduce of 8 per-thread partials; writes knr AND the
// normalized bf16 keys in MFMA-A-fragment tile order:
// (((h*512+t)*4+ks)*64+lane)*8 elems hold kmem[h][t*32+(lane&31)][ks*16+(lane>>5)*8+j]*rn.
// ---------------------------------------------------------------------------
__global__ __launch_bounds__(256)
void kprep_kernel(const float* __restrict__ kmem,
                  float* __restrict__ knr,
                  unsigned short* __restrict__ kbf) {
    __shared__ float ssl[256];
    const int tid = threadIdx.x;
    const int gid = blockIdx.x * 256 + tid;
    const int lane = gid & 63;
    const int ks   = (gid >> 6) & 3;
    const int t    = (gid >> 8) & 511;
    const int h    = gid >> 17;
    const int r    = lane & 31;
    const int hi   = lane >> 5;
    const int row  = t * 32 + r;
    const int d0   = ks * 16 + hi * 8;

    const float* src = kmem + (((size_t)h * MMEM + row) << 6) + d0;
    float4 v0 = *(const float4*)(src);
    float4 v1 = *(const float4*)(src + 4);
    float ss = SS(v0) + SS(v1);
    ssl[r * 8 + ks * 2 + hi] = ss;
    __syncthreads();
    float tot = ssl[r*8+0] + ssl[r*8+1] + ssl[r*8+2] + ssl[r*8+3]
              + ssl[r*8+4] + ssl[r*8+5] + ssl[r*8+6] + ssl[r*8+7];
    const float rn = 1.0f / fmaxf(sqrtf(tot), EPS);
    if (ks == 0 && hi == 0) knr[h * MMEM + row] = rn;

    uint4 o;
    o.x = (unsigned)f2bf(v0.x * rn) | ((unsigned)f2bf(v0.y * rn) << 16);
    o.y = (unsigned)f2bf(v0.z * rn) | ((unsigned)f2bf(v0.w * rn) << 16);
    o.z = (unsigned)f2bf(v1.x * rn) | ((unsigned)f2bf(v1.y * rn) << 16);
    o.w = (unsigned)f2bf(v1.z * rn) | ((unsigned)f2bf(v1.w * rn) << 16);
    *(uint4*)(kbf + (size_t)gid * 8) = o;
}

// ---------------------------------------------------------------------------
// Shared scan helpers
// ---------------------------------------------------------------------------
#define MAX16(ACC)                                                            \
    fmaxf(fmaxf(fmaxf(fmaxf(ACC[0],ACC[1]),fmaxf(ACC[2],ACC[3])),             \
                fmaxf(fmaxf(ACC[4],ACC[5]),fmaxf(ACC[6],ACC[7]))),            \
          fmaxf(fmaxf(fmaxf(ACC[8],ACC[9]),fmaxf(ACC[10],ACC[11])),           \
                fmaxf(fmaxf(ACC[12],ACC[13]),fmaxf(ACC[14],ACC[15]))))

__device__ inline void ins8(float (&tv)[8], float v) {
#pragma unroll
    for (int j = 0; j < 8; ++j) {
        float h_ = fmaxf(tv[j], v);
        float l_ = fminf(tv[j], v);
        tv[j] = h_;
        v = l_;
    }
}

__device__ inline void ins8u(unsigned (&tv)[8], unsigned v) {
#pragma unroll
    for (int j = 0; j < 8; ++j) {
        unsigned h_ = tv[j] > v ? tv[j] : v;
        unsigned l_ = tv[j] > v ? v : tv[j];
        tv[j] = h_;
        v = l_;
    }
}

__device__ inline bf16x8 pack8f(float4 a, float4 b) {
    bf16x8 f;
    f[0] = (short)f2bf(a.x); f[1] = (short)f2bf(a.y);
    f[2] = (short)f2bf(a.z); f[3] = (short)f2bf(a.w);
    f[4] = (short)f2bf(b.x); f[5] = (short)f2bf(b.y);
    f[6] = (short)f2bf(b.z); f[7] = (short)f2bf(b.w);
    return f;
}

#define MFMA8(AF0, AF1, AF2, AF3)                                             \
    f32x16 accA = {0,0,0,0,0,0,0,0,0,0,0,0,0,0,0,0};                         \
    f32x16 accB = {0,0,0,0,0,0,0,0,0,0,0,0,0,0,0,0};                         \
    accA = __builtin_amdgcn_mfma_f32_32x32x16_bf16(AF0, qA[0], accA, 0, 0, 0);\
    accB = __builtin_amdgcn_mfma_f32_32x32x16_bf16(AF0, qB[0], accB, 0, 0, 0);\
    accA = __builtin_amdgcn_mfma_f32_32x32x16_bf16(AF1, qA[1], accA, 0, 0, 0);\
    accB = __builtin_amdgcn_mfma_f32_32x32x16_bf16(AF1, qB[1], accB, 0, 0, 0);\
    accA = __builtin_amdgcn_mfma_f32_32x32x16_bf16(AF2, qA[2], accA, 0, 0, 0);\
    accB = __builtin_amdgcn_mfma_f32_32x32x16_bf16(AF2, qB[2], accB, 0, 0, 0);\
    accA = __builtin_amdgcn_mfma_f32_32x32x16_bf16(AF3, qA[3], accA, 0, 0, 0);\
    accB = __builtin_amdgcn_mfma_f32_32x32x16_bf16(AF3, qB[3], accB, 0, 0, 0);

// ---------------------------------------------------------------------------
// Kernel 2 (scanA): MFMA pass 1. One wave/block, 64 queries x 2048 mems.
// Writes per-(q,p,half) top-8 tile-half-max KEYS (packed 4x u32 = 16B).
// D-layout: col=lane&31 (query), row=(reg&3)+8*(reg>>2)+4*(lane>>5) (mem).
// ---------------------------------------------------------------------------
__global__ __launch_bounds__(64, 4)
void scanA_kernel(const float* __restrict__ query,
                  const unsigned short* __restrict__ kbf,
                  uint4* __restrict__ pkeys) {
    const int lane = threadIdx.x;
    int bid = blockIdx.x;
    const int p  = bid & 7;   bid >>= 3;
    const int qg = bid & 15;  bid >>= 4;
    const int h  = bid;
    const int col = lane & 31;
    const int hi  = lane >> 5;
    const int n0  = qg * 64 + col;
    const int n1  = n0 + 32;

    bf16x8 qA[4], qB[4];
    {
        const int b0 = n0 >> 9, s0 = n0 & 511;
        const int b1 = n1 >> 9, s1 = n1 & 511;
        const float* qp0 = query + ((((size_t)b0 * NHEADS + h) * SEQ + s0) << 6);
        const float* qp1 = query + ((((size_t)b1 * NHEADS + h) * SEQ + s1) << 6);
#pragma unroll
        for (int ks = 0; ks < 4; ++ks) {
            const int d0 = ks * 16 + hi * 8;
            qA[ks] = pack8f(*(const float4*)(qp0 + d0), *(const float4*)(qp0 + d0 + 4));
            qB[ks] = pack8f(*(const float4*)(qp1 + d0), *(const float4*)(qp1 + d0 + 4));
        }
    }

    float tvA[8], tvB[8];
#pragma unroll
    for (int j = 0; j < 8; ++j) { tvA[j] = -1e30f; tvB[j] = -1e30f; }

    const unsigned char* ptr = (const unsigned char*)kbf
        + ((size_t)h * 512 + (size_t)p * NT) * 4096 + (size_t)lane * 16;

    bf16x8 aX0, aX1, aX2, aX3, aY0, aY1, aY2, aY3;
    aX0 = *(const bf16x8*)(ptr);
    aX1 = *(const bf16x8*)(ptr + 1024);
    aX2 = *(const bf16x8*)(ptr + 2048);
    aX3 = *(const bf16x8*)(ptr + 3072);

#pragma unroll 1
    for (int t = 0; t < NT; t += 2) {
        {
            const unsigned char* pn = ptr + (size_t)(t + 1) * 4096;
            aY0 = *(const bf16x8*)(pn);
            aY1 = *(const bf16x8*)(pn + 1024);
            aY2 = *(const bf16x8*)(pn + 2048);
            aY3 = *(const bf16x8*)(pn + 3072);
        }
        {
            MFMA8(aX0, aX1, aX2, aX3)
            ins8(tvA, MAX16(accA));
            ins8(tvB, MAX16(accB));
        }
        if (t + 2 < NT) {
            const unsigned char* p2 = ptr + (size_t)(t + 2) * 4096;
            aX0 = *(const bf16x8*)(p2);
            aX1 = *(const bf16x8*)(p2 + 1024);
            aX2 = *(const bf16x8*)(p2 + 2048);
            aX3 = *(const bf16x8*)(p2 + 3072);
        }
        {
            MFMA8(aY0, aY1, aY2, aY3)
            ins8(tvA, MAX16(accA));
            ins8(tvB, MAX16(accB));
        }
    }

    const int g = p * 2 + hi;
    uint4 oA, oB;
    oA.x = vkey(tvA[0]) | (vkey(tvA[1]) << 16);
    oA.y = vkey(tvA[2]) | (vkey(tvA[3]) << 16);
    oA.z = vkey(tvA[4]) | (vkey(tvA[5]) << 16);
    oA.w = vkey(tvA[6]) | (vkey(tvA[7]) << 16);
    oB.x = vkey(tvB[0]) | (vkey(tvB[1]) << 16);
    oB.y = vkey(tvB[2]) | (vkey(tvB[3]) << 16);
    oB.z = vkey(tvB[4]) | (vkey(tvB[5]) << 16);
    oB.w = vkey(tvB[6]) | (vkey(tvB[7]) << 16);
    pkeys[((size_t)h * NQ + n0) * 16 + g] = oA;
    pkeys[((size_t)h * NQ + n1) * 16 + g] = oB;
}

// ---------------------------------------------------------------------------
// Kernel 3 (taured): per query, exact 8th-largest of its 128 tile-half-max
// keys -> tau_q (a real value of that query, so tau_q <= v8: superset-safe).
// ---------------------------------------------------------------------------
__global__ __launch_bounds__(256)
void taured_kernel(const uint4* __restrict__ pkeys,
                   float* __restrict__ tauv) {
    const int gid = blockIdx.x * 256 + threadIdx.x;   // query id h*NQ+n
    unsigned tvk[8];
#pragma unroll
    for (int j = 0; j < 8; ++j) tvk[j] = 0u;
#pragma unroll
    for (int k = 0; k < 16; ++k) {
        uint4 v = pkeys[(size_t)gid * 16 + k];
        ins8u(tvk, v.x & 0xFFFFu); ins8u(tvk, v.x >> 16);
        ins8u(tvk, v.y & 0xFFFFu); ins8u(tvk, v.y >> 16);
        ins8u(tvk, v.z & 0xFFFFu); ins8u(tvk, v.z >> 16);
        ins8u(tvk, v.w & 0xFFFFu); ins8u(tvk, v.w >> 16);
    }
    tauv[gid] = vunkey(tvk[7]);
}

// ---------------------------------------------------------------------------
// Kernel 4 (scanB): MFMA pass 2, emit mem indices with bf16-score >=
// tau_q - margin_q (margin = 2*2^-8*||q|| + 0.01 covers bf16 rounding of
// both operands -> emitted set provably contains the fp32 top-8).
// Emission via per-lane 16-bit trigger mask + ffs decode (rare body).
// ---------------------------------------------------------------------------
__global__ __launch_bounds__(64, 4)
void scanB_kernel(const float* __restrict__ query,
                  const unsigned short* __restrict__ kbf,
                  const float* __restrict__ tauv,
                  unsigned* __restrict__ pcand,
                  unsigned* __restrict__ pcnt) {
    const int lane = threadIdx.x;
    int bid = blockIdx.x;
    const int p  = bid & 7;   bid >>= 3;
    const int qg = bid & 15;  bid >>= 4;
    const int h  = bid;
    const int col = lane & 31;
    const int hi  = lane >> 5;
    const int n0  = qg * 64 + col;
    const int n1  = n0 + 32;

    bf16x8 qA[4], qB[4];
    float ssA = 0.f, ssB = 0.f;
    {
        const int b0 = n0 >> 9, s0 = n0 & 511;
        const int b1 = n1 >> 9, s1 = n1 & 511;
        const float* qp0 = query + ((((size_t)b0 * NHEADS + h) * SEQ + s0) << 6);
        const float* qp1 = query + ((((size_t)b1 * NHEADS + h) * SEQ + s1) << 6);
#pragma unroll
        for (int ks = 0; ks < 4; ++ks) {
            const int d0 = ks * 16 + hi * 8;
            float4 a0 = *(const float4*)(qp0 + d0), b0v = *(const float4*)(qp0 + d0 + 4);
            float4 a1 = *(const float4*)(qp1 + d0), b1v = *(const float4*)(qp1 + d0 + 4);
            ssA += SS(a0) + SS(b0v);
            ssB += SS(a1) + SS(b1v);
            qA[ks] = pack8f(a0, b0v);
            qB[ks] = pack8f(a1, b1v);
        }
    }
    ssA += __shfl_xor(ssA, 32);   // other half's dims (same query)
    ssB += __shfl_xor(ssB, 32);
    const float tA = tauv[h * NQ + n0] - (sqrtf(ssA) * 0.0078125f + 0.01f);
    const float tB = tauv[h * NQ + n1] - (sqrtf(ssB) * 0.0078125f + 0.01f);

    const unsigned char* ptr = (const unsigned char*)kbf
        + ((size_t)h * 512 + (size_t)p * NT) * 4096 + (size_t)lane * 16;

    unsigned cA = 0, cB = 0;
    const size_t chA = ((size_t)h * NQ + n0) * 16 + p * 2 + hi;
    const size_t chB = ((size_t)h * NQ + n1) * 16 + p * 2 + hi;
    unsigned* mApt = pcand + chA * CMAX;
    unsigned* mBpt = pcand + chB * CMAX;

#define EMITM(ACC, TAU, C, LST, MBV) do {                                     \
        unsigned _msk = 0;                                                    \
        _Pragma("unroll")                                                     \
        for (int _r = 0; _r < 16; ++_r)                                       \
            _msk |= (ACC[_r] >= (TAU)) ? (1u << _r) : 0u;                     \
        if (_msk) {                                                           \
            do {                                                              \
                int _r = __ffs(_msk) - 1;                                     \
                unsigned _idx = (unsigned)((MBV) + (_r & 3) + 8 * (_r >> 2)); \
                if ((C) < CMAX) (LST)[C] = _idx;                              \
                ++(C);                                                        \
                _msk &= _msk - 1;                                             \
            } while (_msk);                                                   \
        }                                                                     \
    } while (0)

    bf16x8 aX0, aX1, aX2, aX3, aY0, aY1, aY2, aY3;
    aX0 = *(const bf16x8*)(ptr);
    aX1 = *(const bf16x8*)(ptr + 1024);
    aX2 = *(const bf16x8*)(ptr + 2048);
    aX3 = *(const bf16x8*)(ptr + 3072);

#pragma unroll 1
    for (int t = 0; t < NT; t += 2) {
        {
            const unsigned char* pn = ptr + (size_t)(t + 1) * 4096;
            aY0 = *(const bf16x8*)(pn);
            aY1 = *(const bf16x8*)(pn + 1024);
            aY2 = *(const bf16x8*)(pn + 2048);
            aY3 = *(const bf16x8*)(pn + 3072);
        }
        {
            MFMA8(aX0, aX1, aX2, aX3)
            const int mbv = p * 2048 + t * 32 + 4 * hi;
            EMITM(accA, tA, cA, mApt, mbv);
            EMITM(accB, tB, cB, mBpt, mbv);
        }
        if (t + 2 < NT) {
            const unsigned char* p2 = ptr + (size_t)(t + 2) * 4096;
            aX0 = *(const bf16x8*)(p2);
            aX1 = *(const bf16x8*)(p2 + 1024);
            aX2 = *(const bf16x8*)(p2 + 2048);
            aX3 = *(const bf16x8*)(p2 + 3072);
        }
        {
            MFMA8(aY0, aY1, aY2, aY3)
            const int mbv = p * 2048 + (t + 1) * 32 + 4 * hi;
            EMITM(accA, tA, cA, mApt, mbv);
            EMITM(accB, tB, cB, mBpt, mbv);
        }
    }
    pcnt[chA] = cA;
    pcnt[chB] = cB;
#undef EMITM
}

// ---------------------------------------------------------------------------
// Kernel 5 (rescore_merge): one thread per query. fp32-rescore all emitted
// candidates, exact top-8 with (score desc, idx asc) ties, gather V rows,
// sigmoid-gate blend, write. Overflowed queries (never, by margin sizing)
// fall back to an exact full-memory fp32 scan.
// ---------------------------------------------------------------------------
#define KROW(I, Q) kv = kp[I]; \
    a0 = fmaf(Q.x, kv.x, a0); a1 = fmaf(Q.y, kv.y, a1); \
    a2 = fmaf(Q.z, kv.z, a2); a3 = fmaf(Q.w, kv.w, a3);
#define DOT64()                                                  \
    float a0 = 0.f, a1 = 0.f, a2 = 0.f, a3 = 0.f;                \
    float4 kv;                                                   \
    KROW(0, q0)  KROW(1, q1)  KROW(2, q2)  KROW(3, q3)           \
    KROW(4, q4)  KROW(5, q5)  KROW(6, q6)  KROW(7, q7)           \
    KROW(8, q8)  KROW(9, q9)  KROW(10, q10) KROW(11, q11)        \
    KROW(12, q12) KROW(13, q13) KROW(14, q14) KROW(15, q15)
#define TINS(SC, IDX)                                                         \
    if ((SC) > tv[7] || ((SC) == tv[7] && (IDX) < ti[7])) {                   \
        tv[7] = (SC); ti[7] = (IDX);                                          \
        _Pragma("unroll")                                                     \
        for (int _j = 7; _j > 0; --_j) {                                      \
            bool _sw = (tv[_j] > tv[_j-1]) ||                                 \
                       (tv[_j] == tv[_j-1] && ti[_j] < ti[_j-1]);             \
            if (_sw) {                                                        \
                float _tf = tv[_j]; tv[_j] = tv[_j-1]; tv[_j-1] = _tf;        \
                int   _tu = ti[_j]; ti[_j] = ti[_j-1]; ti[_j-1] = _tu;        \
            }                                                                 \
        }                                                                     \
    }

__global__ __launch_bounds__(256, 2)
void rescore_merge_kernel(const float* __restrict__ query,
                          const float* __restrict__ kmem,
                          const float* __restrict__ knr,
                          const unsigned* __restrict__ pcand,
                          const unsigned* __restrict__ pcnt,
                          const float* __restrict__ vmem,
                          const float* __restrict__ outputs,
                          const float* __restrict__ gate,
                          float* __restrict__ out) {
    const int gid = blockIdx.x * 256 + threadIdx.x;   // query id
    const int h = gid >> 10;
    const int n = gid & 1023;
    const int b = n >> 9;
    const int s = n & 511;

    const float4* qv = (const float4*)(query + ((((size_t)b * NHEADS + h) * SEQ + s) << 6));
    float4 q0 = qv[0],  q1 = qv[1],  q2 = qv[2],  q3 = qv[3];
    float4 q4 = qv[4],  q5 = qv[5],  q6 = qv[6],  q7 = qv[7];
    float4 q8 = qv[8],  q9 = qv[9],  q10 = qv[10], q11 = qv[11];
    float4 q12 = qv[12], q13 = qv[13], q14 = qv[14], q15 = qv[15];
    float ss = SS(q0)+SS(q1)+SS(q2)+SS(q3)+SS(q4)+SS(q5)+SS(q6)+SS(q7)
             + SS(q8)+SS(q9)+SS(q10)+SS(q11)+SS(q12)+SS(q13)+SS(q14)+SS(q15);
    const float qs = 1.0f / (fmaxf(sqrtf(ss), EPS) * 8.0f);

    float tv[8]; int ti[8];
#pragma unroll
    for (int j = 0; j < 8; ++j) { tv[j] = -1e30f; ti[j] = 0x7fffffff; }

    const float* kb = kmem + ((size_t)h << 20);
    const float* nb = knr + h * MMEM;

    bool ovf = false;
#pragma unroll
    for (int g = 0; g < 16; ++g) ovf |= (pcnt[(size_t)gid * 16 + g] > CMAX);

    if (ovf) {
        // exact fallback: full-memory fp32 scan (practically never taken)
#pragma unroll 1
        for (int m = 0; m < MMEM; ++m) {
            const float4* kp = (const float4*)(kb + ((size_t)m << 6));
            DOT64()
            const float sc = ((a0 + a1) + (a2 + a3)) * qs * nb[m];
            TINS(sc, m)
        }
    } else {
#pragma unroll 1
        for (int g = 0; g < 16; ++g) {
            const unsigned cg = pcnt[(size_t)gid * 16 + g];
            const unsigned* lp = pcand + ((size_t)gid * 16 + g) * CMAX;
#pragma unroll 1
            for (unsigned c = 0; c < cg; ++c) {
                const int idx = (int)lp[c];
                const float4* kp = (const float4*)(kb + ((size_t)idx << 6));
                DOT64()
                const float sc = ((a0 + a1) + (a2 + a3)) * qs * nb[idx];
                TINS(sc, idx)
            }
        }
    }

    float4 acc[16];
#pragma unroll
    for (int i = 0; i < 16; ++i) acc[i] = make_float4(0.f, 0.f, 0.f, 0.f);
#pragma unroll
    for (int j = 0; j < 8; ++j) {
        const float4* vp = (const float4*)(vmem + (((size_t)h * MMEM + ti[j]) << 6));
        const float sc = tv[j];
#pragma unroll
        for (int i = 0; i < 16; ++i) {
            float4 v = vp[i];
            acc[i].x = fmaf(sc, v.x, acc[i].x);
            acc[i].y = fmaf(sc, v.y, acc[i].y);
            acc[i].z = fmaf(sc, v.z, acc[i].z);
            acc[i].w = fmaf(sc, v.w, acc[i].w);
        }
    }

    const float gg = 1.0f / (1.0f + expf(-gate[h]));
    const float og = 1.0f - gg;
    const size_t off = (((size_t)b * NHEADS + h) * SEQ + s) << 6;
    const float4* op = (const float4*)(outputs + off);
    float4* dst = (float4*)(out + off);
#pragma unroll
    for (int i = 0; i < 16; ++i) {
        float4 o = op[i];
        float4 rr;
        rr.x = gg * acc[i].x + og * o.x;
        rr.y = gg * acc[i].y + og * o.y;
        rr.z = gg * acc[i].z + og * o.z;
        rr.w = gg * acc[i].w + og * o.w;
        dst[i] = rr;
    }
}

// ---------------------------------------------------------------------------
// Fallback path (ws too small): fp32 scan + merge (previous rounds').
// ---------------------------------------------------------------------------
__global__ void knorm_kernel(const float* __restrict__ kmem,
                             float* __restrict__ knr) {
    int gid = blockIdx.x * 256 + threadIdx.x;
    int mem = gid >> 4;
    int d4  = gid & 15;
    float4 kv = reinterpret_cast<const float4*>(kmem)[(size_t)mem * 16 + d4];
    float ss = SS(kv);
    ss += __shfl_xor(ss, 1);
    ss += __shfl_xor(ss, 2);
    ss += __shfl_xor(ss, 4);
    ss += __shfl_xor(ss, 8);
    if (d4 == 0) knr[mem] = 1.0f / fmaxf(sqrtf(ss), EPS);
}

__global__ __launch_bounds__(64, 4)
void scan_kernel(const float* __restrict__ query,
                 const float* __restrict__ kmem,
                 const float* __restrict__ knr,
                 float* __restrict__ pscore,
                 int* __restrict__ pidx,
                 int P, int CH) {
    const int lane = threadIdx.x & 63;
    int bid = blockIdx.x;
    const int p  = bid % P;  bid /= P;
    const int qb = bid & 15; bid >>= 4;
    const int h  = bid;
    const int n  = qb * 64 + lane;
    const int b  = n >> 9;
    const int s  = n & 511;

    const float4* qp = reinterpret_cast<const float4*>(
        query + (((size_t)b * NHEADS + h) * SEQ + s) * HD);
    float q[HD];
    float ss = 0.0f;
#pragma unroll
    for (int i = 0; i < 16; ++i) {
        float4 v = qp[i];
        q[4*i+0] = v.x; q[4*i+1] = v.y; q[4*i+2] = v.z; q[4*i+3] = v.w;
        ss += SS(v);
    }
    const float rq = 1.0f / (fmaxf(sqrtf(ss), EPS) * 8.0f);
#pragma unroll
    for (int i = 0; i < HD; ++i) q[i] *= rq;

    float tv[8]; int ti[8];
#pragma unroll
    for (int j = 0; j < 8; ++j) { tv[j] = -INFINITY; ti[j] = 0; }

    const int m0 = p * CH;
    const float4* kp = reinterpret_cast<const float4*>(
        kmem + ((size_t)h * MMEM + m0) * HD);
    const float* knrp = knr + h * MMEM + m0;

    for (int mm = 0; mm < CH; ++mm) {
        float d0 = 0.f, d1 = 0.f, d2 = 0.f, d3 = 0.f;
#pragma unroll
        for (int i = 0; i < 16; ++i) {
            float4 kv = kp[(size_t)mm * 16 + i];
            d0 = fmaf(q[4*i+0], kv.x, d0);
            d1 = fmaf(q[4*i+1], kv.y, d1);
            d2 = fmaf(q[4*i+2], kv.z, d2);
            d3 = fmaf(q[4*i+3], kv.w, d3);
        }
        const float sim = ((d0 + d1) + (d2 + d3)) * knrp[mm];
        if (sim > tv[7]) {
            tv[7] = sim; ti[7] = m0 + mm;
#pragma unroll
            for (int j = 7; j > 0; --j) {
                if (tv[j] > tv[j-1]) {
                    float tf = tv[j]; tv[j] = tv[j-1]; tv[j-1] = tf;
                    int   tu = ti[j]; ti[j] = ti[j-1]; ti[j-1] = tu;
                }
            }
        }
    }

    const size_t base = (((size_t)h * NQ + n) * P + p) * 8;
#pragma unroll
    for (int j = 0; j < 8; ++j) { pscore[base+j] = tv[j]; pidx[base+j] = ti[j]; }
}

__global__ void merge_kernel(const float* __restrict__ pscore,
                             const int* __restrict__ pidx,
                             const float* __restrict__ vmem,
                             const float* __restrict__ outputs,
                             const float* __restrict__ gate,
                             float* __restrict__ out, int P) {
    const int t = blockIdx.x * 256 + threadIdx.x;
    const int h = t >> 10;
    const int n = t & 1023;
    const int b = n >> 9;
    const int s = n & 511;

    float tv[8]; int ti[8];
    const size_t base = ((size_t)h * NQ + n) * P * 8;
#pragma unroll
    for (int j = 0; j < 8; ++j) { tv[j] = pscore[base + j]; ti[j] = pidx[base + j]; }
    const int total = P * 8;
    for (int c = 8; c < total; ++c) {
        const float v = pscore[base + c];
        if (v > tv[7]) {
            tv[7] = v; ti[7] = pidx[base + c];
#pragma unroll
            for (int j = 7; j > 0; --j) {
                if (tv[j] > tv[j-1]) {
                    float tf = tv[j]; tv[j] = tv[j-1]; tv[j-1] = tf;
                    int   tu = ti[j]; ti[j] = ti[j-1]; ti[j-1] = tu;
                }
            }
        }
    }

    float4 acc[16];
#pragma unroll
    for (int i = 0; i < 16; ++i) acc[i] = make_float4(0.f, 0.f, 0.f, 0.f);
#pragma unroll
    for (int j = 0; j < 8; ++j) {
        const float4* vp = reinterpret_cast<const float4*>(
            vmem + ((size_t)h * MMEM + ti[j]) * HD);
        const float sc = tv[j];
#pragma unroll
        for (int i = 0; i < 16; ++i) {
            float4 v = vp[i];
            acc[i].x = fmaf(sc, v.x, acc[i].x);
            acc[i].y = fmaf(sc, v.y, acc[i].y);
            acc[i].z = fmaf(sc, v.z, acc[i].z);
            acc[i].w = fmaf(sc, v.w, acc[i].w);
        }
    }

    const float g  = 1.0f / (1.0f + expf(-gate[h]));
    const float og = 1.0f - g;
    const size_t off = (((size_t)b * NHEADS + h) * SEQ + s) * HD;
    const float4* op = reinterpret_cast<const float4*>(outputs + off);
    float4* dst = reinterpret_cast<float4*>(out + off);
#pragma unroll
    for (int i = 0; i < 16; ++i) {
        float4 o = op[i];
        float4 r;
        r.x = g * acc[i].x + og * o.x;
        r.y = g * acc[i].y + og * o.y;
        r.z = g * acc[i].z + og * o.z;
        r.w = g * acc[i].w + og * o.w;
        dst[i] = r;
    }
}

// ---------------------------------------------------------------------------
extern "C" void kernel_launch(void* const* d_in, const int* in_sizes, int n_in,
                              void* d_out, int out_size, void* d_ws, size_t ws_size,
                              hipStream_t stream) {
    const float* query   = (const float*)d_in[1];
    const float* outputs = (const float*)d_in[4];
    const float* gate    = (const float*)d_in[5];
    const float* kmem    = (const float*)d_in[6];
    const float* vmem    = (const float*)d_in[7];
    float* out = (float*)d_out;

    const size_t NQTOT    = (size_t)NHEADS * NQ;                 // 16384 queries
    const size_t sz_knr   = (size_t)NHEADS * MMEM * 4;           //  1.0 MB
    const size_t sz_kbf   = (size_t)NHEADS * MMEM * HD * 2;      // 33.5 MB
    const size_t sz_pkeys = NQTOT * 16 * 16;                     //  4.2 MB
    const size_t sz_tauv  = NQTOT * 4;                           //  0.07 MB
    const size_t sz_pcand = NQTOT * 16 * CMAX * 4;               // 16.8 MB
    const size_t sz_pcnt  = NQTOT * 16 * 4;                      //  1.0 MB
    const size_t need = sz_knr + sz_kbf + sz_pkeys + sz_tauv + sz_pcand + sz_pcnt;

    if (ws_size >= need) {
        char* w = (char*)d_ws;
        float*          knr   = (float*)w;          w += sz_knr;
        unsigned short* kbf   = (unsigned short*)w; w += sz_kbf;
        uint4*          pkeys = (uint4*)w;          w += sz_pkeys;
        float*          tauv  = (float*)w;          w += sz_tauv;
        unsigned*       pcand = (unsigned*)w;       w += sz_pcand;
        unsigned*       pcnt  = (unsigned*)w;

        kprep_kernel<<<(NHEADS * 512 * 4 * 64) / 256, 256, 0, stream>>>(kmem, knr, kbf);
        scanA_kernel<<<NHEADS * 16 * NPART, 64, 0, stream>>>(query, kbf, pkeys);
        taured_kernel<<<(int)(NQTOT / 256), 256, 0, stream>>>(pkeys, tauv);
        scanB_kernel<<<NHEADS * 16 * NPART, 64, 0, stream>>>(query, kbf, tauv, pcand, pcnt);
        rescore_merge_kernel<<<(int)(NQTOT / 256), 256, 0, stream>>>(
            query, kmem, knr, pcand, pcnt, vmem, outputs, gate, out);
    } else {
        int P = 16;
        while (P > 4 &&
               (size_t)NHEADS * MMEM * 4 + (size_t)NHEADS * NQ * (size_t)P * 64 > ws_size)
            P >>= 1;
        const int CH = MMEM / P;

        float* knr    = (float*)d_ws;
        float* pscore = knr + (size_t)NHEADS * MMEM;
        int*   pidx   = (int*)(pscore + (size_t)NHEADS * NQ * (size_t)P * 8);

        knorm_kernel<<<(NHEADS * MMEM * 16) / 256, 256, 0, stream>>>(kmem, knr);
        scan_kernel<<<NHEADS * 16 * P, 64, 0, stream>>>(
            query, kmem, knr, pscore, pidx, P, CH);
        merge_kernel<<<(NHEADS * NQ) / 256, 256, 0, stream>>>(
            pscore, pidx, vmem, outputs, gate, out, P);
    }
}

// Round 9
// 168.781 us; speedup vs baseline: 2.1810x; 1.7028x over previous
//
#include <hip/hip_runtime.h>
#include <math.h>

#define NHEADS 16
#define HD 64
#define MMEM 16384
#define NQ 1024   // B*S per head
#define SEQ 512
#define EPS 1e-8f
#define NPART 8
#define NT 64     // 32-mem tiles per partition
#define CMAX 16   // candidate slots per (query, partition, lane-half)

typedef short bf16x8 __attribute__((ext_vector_type(8)));
typedef float f32x16 __attribute__((ext_vector_type(16)));

__device__ inline unsigned short f2bf(float f) {
    unsigned int u = __builtin_bit_cast(unsigned int, f);
    unsigned int r = (u + 0x7FFFu + ((u >> 16) & 1u)) >> 16;  // RNE
    return (unsigned short)r;
}

// monotone 16-bit key for raw bf16-dot v (domain clamped to [-8, ~16))
__device__ inline unsigned vkey(float v) {
    float f = fmaf(v, 0.125f, 2.0f);
    f = fminf(fmaxf(f, 1.0f), 3.9999998f);
    return (__builtin_bit_cast(unsigned, f) - 0x3F800000u) >> 8;
}
__device__ inline float vunkey(unsigned k) {
    float f = __builtin_bit_cast(float, (k << 8) + 0x3F800000u);
    return (f - 2.0f) * 8.0f;
}

#define SS(Q) (Q.x*Q.x + Q.y*Q.y + Q.z*Q.z + Q.w*Q.w)

// ---------------------------------------------------------------------------
// Kernel 1: fused knorm + kprep. Block = one (h, tile): 32 rows x 64 d.
// Row 1/||k|| via LDS reduce of 8 per-thread partials; writes knr AND the
// normalized bf16 keys in MFMA-A-fragment tile order:
// (((h*512+t)*4+ks)*64+lane)*8 elems hold kmem[h][t*32+(lane&31)][ks*16+(lane>>5)*8+j]*rn.
// ---------------------------------------------------------------------------
__global__ __launch_bounds__(256)
void kprep_kernel(const float* __restrict__ kmem,
                  float* __restrict__ knr,
                  unsigned short* __restrict__ kbf) {
    __shared__ float ssl[256];
    const int tid = threadIdx.x;
    const int gid = blockIdx.x * 256 + tid;
    const int lane = gid & 63;
    const int ks   = (gid >> 6) & 3;
    const int t    = (gid >> 8) & 511;
    const int h    = gid >> 17;
    const int r    = lane & 31;
    const int hi   = lane >> 5;
    const int row  = t * 32 + r;
    const int d0   = ks * 16 + hi * 8;

    const float* src = kmem + (((size_t)h * MMEM + row) << 6) + d0;
    float4 v0 = *(const float4*)(src);
    float4 v1 = *(const float4*)(src + 4);
    float ss = SS(v0) + SS(v1);
    ssl[r * 8 + ks * 2 + hi] = ss;
    __syncthreads();
    float tot = ssl[r*8+0] + ssl[r*8+1] + ssl[r*8+2] + ssl[r*8+3]
              + ssl[r*8+4] + ssl[r*8+5] + ssl[r*8+6] + ssl[r*8+7];
    const float rn = 1.0f / fmaxf(sqrtf(tot), EPS);
    if (ks == 0 && hi == 0) knr[h * MMEM + row] = rn;

    uint4 o;
    o.x = (unsigned)f2bf(v0.x * rn) | ((unsigned)f2bf(v0.y * rn) << 16);
    o.y = (unsigned)f2bf(v0.z * rn) | ((unsigned)f2bf(v0.w * rn) << 16);
    o.z = (unsigned)f2bf(v1.x * rn) | ((unsigned)f2bf(v1.y * rn) << 16);
    o.w = (unsigned)f2bf(v1.z * rn) | ((unsigned)f2bf(v1.w * rn) << 16);
    *(uint4*)(kbf + (size_t)gid * 8) = o;
}

// ---------------------------------------------------------------------------
// Shared scan helpers
// ---------------------------------------------------------------------------
#define MAX16(ACC)                                                            \
    fmaxf(fmaxf(fmaxf(fmaxf(ACC[0],ACC[1]),fmaxf(ACC[2],ACC[3])),             \
                fmaxf(fmaxf(ACC[4],ACC[5]),fmaxf(ACC[6],ACC[7]))),            \
          fmaxf(fmaxf(fmaxf(ACC[8],ACC[9]),fmaxf(ACC[10],ACC[11])),           \
                fmaxf(fmaxf(ACC[12],ACC[13]),fmaxf(ACC[14],ACC[15]))))

__device__ inline void ins8(float (&tv)[8], float v) {
#pragma unroll
    for (int j = 0; j < 8; ++j) {
        float h_ = fmaxf(tv[j], v);
        float l_ = fminf(tv[j], v);
        tv[j] = h_;
        v = l_;
    }
}

__device__ inline void ins8u(unsigned (&tv)[8], unsigned v) {
#pragma unroll
    for (int j = 0; j < 8; ++j) {
        unsigned h_ = tv[j] > v ? tv[j] : v;
        unsigned l_ = tv[j] > v ? v : tv[j];
        tv[j] = h_;
        v = l_;
    }
}

__device__ inline void ins8u64(unsigned long long (&tv)[8], unsigned long long v) {
#pragma unroll
    for (int j = 0; j < 8; ++j) {
        unsigned long long h_ = tv[j] > v ? tv[j] : v;
        unsigned long long l_ = tv[j] > v ? v : tv[j];
        tv[j] = h_;
        v = l_;
    }
}

__device__ inline bf16x8 pack8f(float4 a, float4 b) {
    bf16x8 f;
    f[0] = (short)f2bf(a.x); f[1] = (short)f2bf(a.y);
    f[2] = (short)f2bf(a.z); f[3] = (short)f2bf(a.w);
    f[4] = (short)f2bf(b.x); f[5] = (short)f2bf(b.y);
    f[6] = (short)f2bf(b.z); f[7] = (short)f2bf(b.w);
    return f;
}

#define MFMA8(AF0, AF1, AF2, AF3)                                             \
    f32x16 accA = {0,0,0,0,0,0,0,0,0,0,0,0,0,0,0,0};                         \
    f32x16 accB = {0,0,0,0,0,0,0,0,0,0,0,0,0,0,0,0};                         \
    accA = __builtin_amdgcn_mfma_f32_32x32x16_bf16(AF0, qA[0], accA, 0, 0, 0);\
    accB = __builtin_amdgcn_mfma_f32_32x32x16_bf16(AF0, qB[0], accB, 0, 0, 0);\
    accA = __builtin_amdgcn_mfma_f32_32x32x16_bf16(AF1, qA[1], accA, 0, 0, 0);\
    accB = __builtin_amdgcn_mfma_f32_32x32x16_bf16(AF1, qB[1], accB, 0, 0, 0);\
    accA = __builtin_amdgcn_mfma_f32_32x32x16_bf16(AF2, qA[2], accA, 0, 0, 0);\
    accB = __builtin_amdgcn_mfma_f32_32x32x16_bf16(AF2, qB[2], accB, 0, 0, 0);\
    accA = __builtin_amdgcn_mfma_f32_32x32x16_bf16(AF3, qA[3], accA, 0, 0, 0);\
    accB = __builtin_amdgcn_mfma_f32_32x32x16_bf16(AF3, qB[3], accB, 0, 0, 0);

// ---------------------------------------------------------------------------
// Kernel 2 (scanA): MFMA pass 1. One wave/block, 64 queries x 2048 mems.
// Writes per-(q,p,half) top-8 tile-half-max KEYS (packed 4x u32 = 16B).
// D-layout: col=lane&31 (query), row=(reg&3)+8*(reg>>2)+4*(lane>>5) (mem).
// ---------------------------------------------------------------------------
__global__ __launch_bounds__(64, 4)
void scanA_kernel(const float* __restrict__ query,
                  const unsigned short* __restrict__ kbf,
                  uint4* __restrict__ pkeys) {
    const int lane = threadIdx.x;
    int bid = blockIdx.x;
    const int p  = bid & 7;   bid >>= 3;
    const int qg = bid & 15;  bid >>= 4;
    const int h  = bid;
    const int col = lane & 31;
    const int hi  = lane >> 5;
    const int n0  = qg * 64 + col;
    const int n1  = n0 + 32;

    bf16x8 qA[4], qB[4];
    {
        const int b0 = n0 >> 9, s0 = n0 & 511;
        const int b1 = n1 >> 9, s1 = n1 & 511;
        const float* qp0 = query + ((((size_t)b0 * NHEADS + h) * SEQ + s0) << 6);
        const float* qp1 = query + ((((size_t)b1 * NHEADS + h) * SEQ + s1) << 6);
#pragma unroll
        for (int ks = 0; ks < 4; ++ks) {
            const int d0 = ks * 16 + hi * 8;
            qA[ks] = pack8f(*(const float4*)(qp0 + d0), *(const float4*)(qp0 + d0 + 4));
            qB[ks] = pack8f(*(const float4*)(qp1 + d0), *(const float4*)(qp1 + d0 + 4));
        }
    }

    float tvA[8], tvB[8];
#pragma unroll
    for (int j = 0; j < 8; ++j) { tvA[j] = -1e30f; tvB[j] = -1e30f; }

    const unsigned char* ptr = (const unsigned char*)kbf
        + ((size_t)h * 512 + (size_t)p * NT) * 4096 + (size_t)lane * 16;

    bf16x8 aX0, aX1, aX2, aX3, aY0, aY1, aY2, aY3;
    aX0 = *(const bf16x8*)(ptr);
    aX1 = *(const bf16x8*)(ptr + 1024);
    aX2 = *(const bf16x8*)(ptr + 2048);
    aX3 = *(const bf16x8*)(ptr + 3072);

#pragma unroll 1
    for (int t = 0; t < NT; t += 2) {
        {
            const unsigned char* pn = ptr + (size_t)(t + 1) * 4096;
            aY0 = *(const bf16x8*)(pn);
            aY1 = *(const bf16x8*)(pn + 1024);
            aY2 = *(const bf16x8*)(pn + 2048);
            aY3 = *(const bf16x8*)(pn + 3072);
        }
        {
            MFMA8(aX0, aX1, aX2, aX3)
            ins8(tvA, MAX16(accA));
            ins8(tvB, MAX16(accB));
        }
        if (t + 2 < NT) {
            const unsigned char* p2 = ptr + (size_t)(t + 2) * 4096;
            aX0 = *(const bf16x8*)(p2);
            aX1 = *(const bf16x8*)(p2 + 1024);
            aX2 = *(const bf16x8*)(p2 + 2048);
            aX3 = *(const bf16x8*)(p2 + 3072);
        }
        {
            MFMA8(aY0, aY1, aY2, aY3)
            ins8(tvA, MAX16(accA));
            ins8(tvB, MAX16(accB));
        }
    }

    const int g = p * 2 + hi;
    uint4 oA, oB;
    oA.x = vkey(tvA[0]) | (vkey(tvA[1]) << 16);
    oA.y = vkey(tvA[2]) | (vkey(tvA[3]) << 16);
    oA.z = vkey(tvA[4]) | (vkey(tvA[5]) << 16);
    oA.w = vkey(tvA[6]) | (vkey(tvA[7]) << 16);
    oB.x = vkey(tvB[0]) | (vkey(tvB[1]) << 16);
    oB.y = vkey(tvB[2]) | (vkey(tvB[3]) << 16);
    oB.z = vkey(tvB[4]) | (vkey(tvB[5]) << 16);
    oB.w = vkey(tvB[6]) | (vkey(tvB[7]) << 16);
    pkeys[((size_t)h * NQ + n0) * 16 + g] = oA;
    pkeys[((size_t)h * NQ + n1) * 16 + g] = oB;
}

// ---------------------------------------------------------------------------
// Kernel 3 (taured): per query, exact 8th-largest of its 128 tile-half-max
// keys -> tau_q (a real value of that query, so tau_q <= v8: superset-safe).
// ---------------------------------------------------------------------------
__global__ __launch_bounds__(256)
void taured_kernel(const uint4* __restrict__ pkeys,
                   float* __restrict__ tauv) {
    const int gid = blockIdx.x * 256 + threadIdx.x;   // query id h*NQ+n
    unsigned tvk[8];
#pragma unroll
    for (int j = 0; j < 8; ++j) tvk[j] = 0u;
#pragma unroll
    for (int k = 0; k < 16; ++k) {
        uint4 v = pkeys[(size_t)gid * 16 + k];
        ins8u(tvk, v.x & 0xFFFFu); ins8u(tvk, v.x >> 16);
        ins8u(tvk, v.y & 0xFFFFu); ins8u(tvk, v.y >> 16);
        ins8u(tvk, v.z & 0xFFFFu); ins8u(tvk, v.z >> 16);
        ins8u(tvk, v.w & 0xFFFFu); ins8u(tvk, v.w >> 16);
    }
    tauv[gid] = vunkey(tvk[7]);
}

// ---------------------------------------------------------------------------
// Kernel 4 (scanB): MFMA pass 2, emit mem indices with bf16-score >=
// tau_q - margin_q (margin = 2*2^-8*||q|| + 0.01 covers bf16 rounding of
// both operands -> emitted set provably contains the fp32 top-8).
// Emission via per-lane 16-bit trigger mask + ffs decode (rare body).
// ---------------------------------------------------------------------------
__global__ __launch_bounds__(64, 4)
void scanB_kernel(const float* __restrict__ query,
                  const unsigned short* __restrict__ kbf,
                  const float* __restrict__ tauv,
                  unsigned* __restrict__ pcand,
                  unsigned* __restrict__ pcnt) {
    const int lane = threadIdx.x;
    int bid = blockIdx.x;
    const int p  = bid & 7;   bid >>= 3;
    const int qg = bid & 15;  bid >>= 4;
    const int h  = bid;
    const int col = lane & 31;
    const int hi  = lane >> 5;
    const int n0  = qg * 64 + col;
    const int n1  = n0 + 32;

    bf16x8 qA[4], qB[4];
    float ssA = 0.f, ssB = 0.f;
    {
        const int b0 = n0 >> 9, s0 = n0 & 511;
        const int b1 = n1 >> 9, s1 = n1 & 511;
        const float* qp0 = query + ((((size_t)b0 * NHEADS + h) * SEQ + s0) << 6);
        const float* qp1 = query + ((((size_t)b1 * NHEADS + h) * SEQ + s1) << 6);
#pragma unroll
        for (int ks = 0; ks < 4; ++ks) {
            const int d0 = ks * 16 + hi * 8;
            float4 a0 = *(const float4*)(qp0 + d0), b0v = *(const float4*)(qp0 + d0 + 4);
            float4 a1 = *(const float4*)(qp1 + d0), b1v = *(const float4*)(qp1 + d0 + 4);
            ssA += SS(a0) + SS(b0v);
            ssB += SS(a1) + SS(b1v);
            qA[ks] = pack8f(a0, b0v);
            qB[ks] = pack8f(a1, b1v);
        }
    }
    ssA += __shfl_xor(ssA, 32);   // other half's dims (same query)
    ssB += __shfl_xor(ssB, 32);
    const float tA = tauv[h * NQ + n0] - (sqrtf(ssA) * 0.0078125f + 0.01f);
    const float tB = tauv[h * NQ + n1] - (sqrtf(ssB) * 0.0078125f + 0.01f);

    const unsigned char* ptr = (const unsigned char*)kbf
        + ((size_t)h * 512 + (size_t)p * NT) * 4096 + (size_t)lane * 16;

    unsigned cA = 0, cB = 0;
    const size_t chA = ((size_t)h * NQ + n0) * 16 + p * 2 + hi;
    const size_t chB = ((size_t)h * NQ + n1) * 16 + p * 2 + hi;
    unsigned* mApt = pcand + chA * CMAX;
    unsigned* mBpt = pcand + chB * CMAX;

#define EMITM(ACC, TAU, C, LST, MBV) do {                                     \
        unsigned _msk = 0;                                                    \
        _Pragma("unroll")                                                     \
        for (int _r = 0; _r < 16; ++_r)                                       \
            _msk |= (ACC[_r] >= (TAU)) ? (1u << _r) : 0u;                     \
        if (_msk) {                                                           \
            do {                                                              \
                int _r = __ffs(_msk) - 1;                                     \
                unsigned _idx = (unsigned)((MBV) + (_r & 3) + 8 * (_r >> 2)); \
                if ((C) < CMAX) (LST)[C] = _idx;                              \
                ++(C);                                                        \
                _msk &= _msk - 1;                                             \
            } while (_msk);                                                   \
        }                                                                     \
    } while (0)

    bf16x8 aX0, aX1, aX2, aX3, aY0, aY1, aY2, aY3;
    aX0 = *(const bf16x8*)(ptr);
    aX1 = *(const bf16x8*)(ptr + 1024);
    aX2 = *(const bf16x8*)(ptr + 2048);
    aX3 = *(const bf16x8*)(ptr + 3072);

#pragma unroll 1
    for (int t = 0; t < NT; t += 2) {
        {
            const unsigned char* pn = ptr + (size_t)(t + 1) * 4096;
            aY0 = *(const bf16x8*)(pn);
            aY1 = *(const bf16x8*)(pn + 1024);
            aY2 = *(const bf16x8*)(pn + 2048);
            aY3 = *(const bf16x8*)(pn + 3072);
        }
        {
            MFMA8(aX0, aX1, aX2, aX3)
            const int mbv = p * 2048 + t * 32 + 4 * hi;
            EMITM(accA, tA, cA, mApt, mbv);
            EMITM(accB, tB, cB, mBpt, mbv);
        }
        if (t + 2 < NT) {
            const unsigned char* p2 = ptr + (size_t)(t + 2) * 4096;
            aX0 = *(const bf16x8*)(p2);
            aX1 = *(const bf16x8*)(p2 + 1024);
            aX2 = *(const bf16x8*)(p2 + 2048);
            aX3 = *(const bf16x8*)(p2 + 3072);
        }
        {
            MFMA8(aY0, aY1, aY2, aY3)
            const int mbv = p * 2048 + (t + 1) * 32 + 4 * hi;
            EMITM(accA, tA, cA, mApt, mbv);
            EMITM(accB, tB, cB, mBpt, mbv);
        }
    }
    pcnt[chA] = cA;
    pcnt[chB] = cB;
#undef EMITM
}

// ---------------------------------------------------------------------------
// Kernel 5 (rescore_merge): ONE WAVE per query (latency fix for R8's 2.6%
// occupancy). Lane d4=lane&15 holds query float4; candidate dot = per-lane
// partial + 4 shfl_xor (all lanes get the score). Exact selection via packed
// u64 keys (monotone(score)<<32 | ~idx): total order = (score desc, idx asc),
// branchless ins8u64, bit-exact score recovery. V-gather: lane i owns output
// element i (8 coalesced row loads). Overflow -> same loop over all mems.
// ---------------------------------------------------------------------------
__global__ __launch_bounds__(64, 8)
void rescore_merge_kernel(const float* __restrict__ query,
                          const float* __restrict__ kmem,
                          const float* __restrict__ knr,
                          const unsigned* __restrict__ pcand,
                          const unsigned* __restrict__ pcnt,
                          const float* __restrict__ vmem,
                          const float* __restrict__ outputs,
                          const float* __restrict__ gate,
                          float* __restrict__ out) {
    __shared__ unsigned cands[16 * CMAX];
    const int gid = blockIdx.x;            // query id
    const int h = gid >> 10;
    const int n = gid & 1023;
    const int b = n >> 9;
    const int s = n & 511;
    const int lane = threadIdx.x;
    const int d4 = lane & 15;

    const float* qbase = query + ((((size_t)b * NHEADS + h) * SEQ + s) << 6);
    const float4 q4 = ((const float4*)qbase)[d4];
    float ssp = SS(q4);
    ssp += __shfl_xor(ssp, 1);
    ssp += __shfl_xor(ssp, 2);
    ssp += __shfl_xor(ssp, 4);
    ssp += __shfl_xor(ssp, 8);     // full ||q||^2 within each 16-lane group
    const float qs = 1.0f / (fmaxf(sqrtf(ssp), EPS) * 8.0f);

    // compact the 16 candidate lists into LDS (16-lane shfl prefix scan)
    const unsigned cg = pcnt[(size_t)gid * 16 + d4];
    const bool anyovf = (__ballot(cg > CMAX) != 0ULL);
    unsigned inc = cg;
#pragma unroll
    for (int d = 1; d < 16; d <<= 1) {
        unsigned t = __shfl_up(inc, d, 16);
        if (d4 >= d) inc += t;
    }
    const unsigned ct = __shfl(inc, 15, 16);
    const unsigned excl = inc - cg;
    if (lane < 16) {
        const unsigned* lp = pcand + ((size_t)gid * 16 + lane) * CMAX;
        const unsigned cc = cg > CMAX ? CMAX : cg;
        for (unsigned c = 0; c < cc; ++c) cands[excl + c] = lp[c];
    }
    __syncthreads();

    const float* kb = kmem + ((size_t)h << 20);
    const float* nb = knr + h * MMEM;

    unsigned long long top[8];
#pragma unroll
    for (int j = 0; j < 8; ++j) top[j] = 0ULL;

#define SCORE_KEY(IDX) ({                                                     \
        float4 kv = ((const float4*)(kb + ((size_t)(IDX) << 6)))[d4];         \
        float d = q4.x*kv.x + q4.y*kv.y + q4.z*kv.z + q4.w*kv.w;              \
        d += __shfl_xor(d, 1);                                                \
        d += __shfl_xor(d, 2);                                                \
        d += __shfl_xor(d, 4);                                                \
        d += __shfl_xor(d, 8);                                                \
        const float sc = d * qs * nb[IDX];                                    \
        unsigned su = __builtin_bit_cast(unsigned, sc);                       \
        unsigned ms = su ^ ((su >> 31) ? 0xFFFFFFFFu : 0x80000000u);          \
        ((unsigned long long)ms << 32) | (0xFFFFFFFFu - (unsigned)(IDX));     \
    })

    if (!anyovf) {
#pragma unroll 1
        for (unsigned c = 0; c < ct; ++c) {
            const unsigned idx = cands[c];
            ins8u64(top, SCORE_KEY(idx));
        }
    } else {
        // exact fallback: all memories (practically never taken)
#pragma unroll 1
        for (int m = 0; m < MMEM; ++m) ins8u64(top, SCORE_KEY(m));
    }
#undef SCORE_KEY

    // V-gather + gate blend: lane owns output element `lane`
    float acc = 0.0f;
    const float* vb = vmem + ((size_t)h << 20);
#pragma unroll
    for (int j = 0; j < 8; ++j) {
        const unsigned long long key = top[j];
        const unsigned idx = 0xFFFFFFFFu - (unsigned)(key & 0xFFFFFFFFu);
        const unsigned ms = (unsigned)(key >> 32);
        const unsigned su = ms ^ ((ms >> 31) ? 0x80000000u : 0xFFFFFFFFu);
        const float sc = __builtin_bit_cast(float, su);
        acc = fmaf(sc, vb[((size_t)idx << 6) + lane], acc);
    }

    const float gg = 1.0f / (1.0f + expf(-gate[h]));
    const size_t off = ((((size_t)b * NHEADS + h) * SEQ + s) << 6) + lane;
    out[off] = gg * acc + (1.0f - gg) * outputs[off];
}

// ---------------------------------------------------------------------------
// Fallback path (ws too small): fp32 scan + merge (previous rounds').
// ---------------------------------------------------------------------------
__global__ void knorm_kernel(const float* __restrict__ kmem,
                             float* __restrict__ knr) {
    int gid = blockIdx.x * 256 + threadIdx.x;
    int mem = gid >> 4;
    int d4  = gid & 15;
    float4 kv = reinterpret_cast<const float4*>(kmem)[(size_t)mem * 16 + d4];
    float ss = SS(kv);
    ss += __shfl_xor(ss, 1);
    ss += __shfl_xor(ss, 2);
    ss += __shfl_xor(ss, 4);
    ss += __shfl_xor(ss, 8);
    if (d4 == 0) knr[mem] = 1.0f / fmaxf(sqrtf(ss), EPS);
}

__global__ __launch_bounds__(64, 4)
void scan_kernel(const float* __restrict__ query,
                 const float* __restrict__ kmem,
                 const float* __restrict__ knr,
                 float* __restrict__ pscore,
                 int* __restrict__ pidx,
                 int P, int CH) {
    const int lane = threadIdx.x & 63;
    int bid = blockIdx.x;
    const int p  = bid % P;  bid /= P;
    const int qb = bid & 15; bid >>= 4;
    const int h  = bid;
    const int n  = qb * 64 + lane;
    const int b  = n >> 9;
    const int s  = n & 511;

    const float4* qp = reinterpret_cast<const float4*>(
        query + (((size_t)b * NHEADS + h) * SEQ + s) * HD);
    float q[HD];
    float ss = 0.0f;
#pragma unroll
    for (int i = 0; i < 16; ++i) {
        float4 v = qp[i];
        q[4*i+0] = v.x; q[4*i+1] = v.y; q[4*i+2] = v.z; q[4*i+3] = v.w;
        ss += SS(v);
    }
    const float rq = 1.0f / (fmaxf(sqrtf(ss), EPS) * 8.0f);
#pragma unroll
    for (int i = 0; i < HD; ++i) q[i] *= rq;

    float tv[8]; int ti[8];
#pragma unroll
    for (int j = 0; j < 8; ++j) { tv[j] = -INFINITY; ti[j] = 0; }

    const int m0 = p * CH;
    const float4* kp = reinterpret_cast<const float4*>(
        kmem + ((size_t)h * MMEM + m0) * HD);
    const float* knrp = knr + h * MMEM + m0;

    for (int mm = 0; mm < CH; ++mm) {
        float d0 = 0.f, d1 = 0.f, d2 = 0.f, d3 = 0.f;
#pragma unroll
        for (int i = 0; i < 16; ++i) {
            float4 kv = kp[(size_t)mm * 16 + i];
            d0 = fmaf(q[4*i+0], kv.x, d0);
            d1 = fmaf(q[4*i+1], kv.y, d1);
            d2 = fmaf(q[4*i+2], kv.z, d2);
            d3 = fmaf(q[4*i+3], kv.w, d3);
        }
        const float sim = ((d0 + d1) + (d2 + d3)) * knrp[mm];
        if (sim > tv[7]) {
            tv[7] = sim; ti[7] = m0 + mm;
#pragma unroll
            for (int j = 7; j > 0; --j) {
                if (tv[j] > tv[j-1]) {
                    float tf = tv[j]; tv[j] = tv[j-1]; tv[j-1] = tf;
                    int   tu = ti[j]; ti[j] = ti[j-1]; ti[j-1] = tu;
                }
            }
        }
    }

    const size_t base = (((size_t)h * NQ + n) * P + p) * 8;
#pragma unroll
    for (int j = 0; j < 8; ++j) { pscore[base+j] = tv[j]; pidx[base+j] = ti[j]; }
}

__global__ void merge_kernel(const float* __restrict__ pscore,
                             const int* __restrict__ pidx,
                             const float* __restrict__ vmem,
                             const float* __restrict__ outputs,
                             const float* __restrict__ gate,
                             float* __restrict__ out, int P) {
    const int t = blockIdx.x * 256 + threadIdx.x;
    const int h = t >> 10;
    const int n = t & 1023;
    const int b = n >> 9;
    const int s = n & 511;

    float tv[8]; int ti[8];
    const size_t base = ((size_t)h * NQ + n) * P * 8;
#pragma unroll
    for (int j = 0; j < 8; ++j) { tv[j] = pscore[base + j]; ti[j] = pidx[base + j]; }
    const int total = P * 8;
    for (int c = 8; c < total; ++c) {
        const float v = pscore[base + c];
        if (v > tv[7]) {
            tv[7] = v; ti[7] = pidx[base + c];
#pragma unroll
            for (int j = 7; j > 0; --j) {
                if (tv[j] > tv[j-1]) {
                    float tf = tv[j]; tv[j] = tv[j-1]; tv[j-1] = tf;
                    int   tu = ti[j]; ti[j] = ti[j-1]; ti[j-1] = tu;
                }
            }
        }
    }

    float4 acc[16];
#pragma unroll
    for (int i = 0; i < 16; ++i) acc[i] = make_float4(0.f, 0.f, 0.f, 0.f);
#pragma unroll
    for (int j = 0; j < 8; ++j) {
        const float4* vp = reinterpret_cast<const float4*>(
            vmem + ((size_t)h * MMEM + ti[j]) * HD);
        const float sc = tv[j];
#pragma unroll
        for (int i = 0; i < 16; ++i) {
            float4 v = vp[i];
            acc[i].x = fmaf(sc, v.x, acc[i].x);
            acc[i].y = fmaf(sc, v.y, acc[i].y);
            acc[i].z = fmaf(sc, v.z, acc[i].z);
            acc[i].w = fmaf(sc, v.w, acc[i].w);
        }
    }

    const float g  = 1.0f / (1.0f + expf(-gate[h]));
    const float og = 1.0f - g;
    const size_t off = (((size_t)b * NHEADS + h) * SEQ + s) * HD;
    const float4* op = reinterpret_cast<const float4*>(outputs + off);
    float4* dst = reinterpret_cast<float4*>(out + off);
#pragma unroll
    for (int i = 0; i < 16; ++i) {
        float4 o = op[i];
        float4 r;
        r.x = g * acc[i].x + og * o.x;
        r.y = g * acc[i].y + og * o.y;
        r.z = g * acc[i].z + og * o.z;
        r.w = g * acc[i].w + og * o.w;
        dst[i] = r;
    }
}

// ---------------------------------------------------------------------------
extern "C" void kernel_launch(void* const* d_in, const int* in_sizes, int n_in,
                              void* d_out, int out_size, void* d_ws, size_t ws_size,
                              hipStream_t stream) {
    const float* query   = (const float*)d_in[1];
    const float* outputs = (const float*)d_in[4];
    const float* gate    = (const float*)d_in[5];
    const float* kmem    = (const float*)d_in[6];
    const float* vmem    = (const float*)d_in[7];
    float* out = (float*)d_out;

    const size_t NQTOT    = (size_t)NHEADS * NQ;                 // 16384 queries
    const size_t sz_knr   = (size_t)NHEADS * MMEM * 4;           //  1.0 MB
    const size_t sz_kbf   = (size_t)NHEADS * MMEM * HD * 2;      // 33.5 MB
    const size_t sz_pkeys = NQTOT * 16 * 16;                     //  4.2 MB
    const size_t sz_tauv  = NQTOT * 4;                           //  0.07 MB
    const size_t sz_pcand = NQTOT * 16 * CMAX * 4;               // 16.8 MB
    const size_t sz_pcnt  = NQTOT * 16 * 4;                      //  1.0 MB
    const size_t need = sz_knr + sz_kbf + sz_pkeys + sz_tauv + sz_pcand + sz_pcnt;

    if (ws_size >= need) {
        char* w = (char*)d_ws;
        float*          knr   = (float*)w;          w += sz_knr;
        unsigned short* kbf   = (unsigned short*)w; w += sz_kbf;
        uint4*          pkeys = (uint4*)w;          w += sz_pkeys;
        float*          tauv  = (float*)w;          w += sz_tauv;
        unsigned*       pcand = (unsigned*)w;       w += sz_pcand;
        unsigned*       pcnt  = (unsigned*)w;

        kprep_kernel<<<(NHEADS * 512 * 4 * 64) / 256, 256, 0, stream>>>(kmem, knr, kbf);
        scanA_kernel<<<NHEADS * 16 * NPART, 64, 0, stream>>>(query, kbf, pkeys);
        taured_kernel<<<(int)(NQTOT / 256), 256, 0, stream>>>(pkeys, tauv);
        scanB_kernel<<<NHEADS * 16 * NPART, 64, 0, stream>>>(query, kbf, tauv, pcand, pcnt);
        rescore_merge_kernel<<<(int)NQTOT, 64, 0, stream>>>(
            query, kmem, knr, pcand, pcnt, vmem, outputs, gate, out);
    } else {
        int P = 16;
        while (P > 4 &&
               (size_t)NHEADS * MMEM * 4 + (size_t)NHEADS * NQ * (size_t)P * 64 > ws_size)
            P >>= 1;
        const int CH = MMEM / P;

        float* knr    = (float*)d_ws;
        float* pscore = knr + (size_t)NHEADS * MMEM;
        int*   pidx   = (int*)(pscore + (size_t)NHEADS * NQ * (size_t)P * 8);

        knorm_kernel<<<(NHEADS * MMEM * 16) / 256, 256, 0, stream>>>(kmem, knr);
        scan_kernel<<<NHEADS * 16 * P, 64, 0, stream>>>(
            query, kmem, knr, pscore, pidx, P, CH);
        merge_kernel<<<(NHEADS * NQ) / 256, 256, 0, stream>>>(
            pscore, pidx, vmem, outputs, gate, out, P);
    }
}

// Round 10
// 149.678 us; speedup vs baseline: 2.4594x; 1.1276x over previous
//
#include <hip/hip_runtime.h>
#include <math.h>

#define NHEADS 16
#define HD 64
#define MMEM 16384
#define NQ 1024   // B*S per head
#define SEQ 512
#define EPS 1e-8f
#define NPART 16
#define NT 32     // 32-mem tiles per partition (16384/16/32)
#define NGRP 32   // candidate groups per query: NPART * 2 halves
#define CMAX 8    // candidate slots per (query, group)

typedef short bf16x8 __attribute__((ext_vector_type(8)));
typedef float f32x16 __attribute__((ext_vector_type(16)));

__device__ inline unsigned short f2bf(float f) {
    unsigned int u = __builtin_bit_cast(unsigned int, f);
    unsigned int r = (u + 0x7FFFu + ((u >> 16) & 1u)) >> 16;  // RNE
    return (unsigned short)r;
}

#define SS(Q) (Q.x*Q.x + Q.y*Q.y + Q.z*Q.z + Q.w*Q.w)

// ---------------------------------------------------------------------------
// Kernel 1: fused knorm + kprep. Block covers 2 (h,tile) pairs: 32 rows x 64 d
// each. Row 1/||k|| via LDS reduce; writes knr AND normalized bf16 keys in
// MFMA-A-fragment tile order:
// (((h*512+t)*4+ks)*64+lane)*8 elems = kmem[h][t*32+(lane&31)][ks*16+(lane>>5)*8+j]*rn.
// ---------------------------------------------------------------------------
__global__ __launch_bounds__(256)
void kprep_kernel(const float* __restrict__ kmem,
                  float* __restrict__ knr,
                  unsigned short* __restrict__ kbf) {
    __shared__ float ssl[256];
    const int tid = threadIdx.x;
    const int gid = blockIdx.x * 256 + tid;
    const int lane = gid & 63;
    const int ks   = (gid >> 6) & 3;
    const int t    = (gid >> 8) & 511;
    const int h    = gid >> 17;
    const int r    = lane & 31;
    const int hi   = lane >> 5;
    const int row  = t * 32 + r;
    const int d0   = ks * 16 + hi * 8;

    const float* src = kmem + (((size_t)h * MMEM + row) << 6) + d0;
    float4 v0 = *(const float4*)(src);
    float4 v1 = *(const float4*)(src + 4);
    float ss = SS(v0) + SS(v1);
    const int lr = tid >> 6;             // local row-block within the 256-blk
    ssl[lr * 64 + r * 2 + 0] = 0.f;      // (layout: 32 rows x 8 slots)
    __syncthreads();                     // (cheap init barrier not needed; overwrite below)
    ssl[(tid & 192) /*lr*64*/ + r * 2 + (ks & 1) + 0] = 0.f;  // placeholder
    __syncthreads();
    // simple exact reduce: each (row) needs sum of its 8 partials
    ssl[(tid >> 6) * 64 + r * 2 + ((ks * 2 + hi) & 1)] = 0.f; // unused
    __syncthreads();
    // --- straightforward version: 8 partials per row in a 32x8 block region
    ssl[tid] = ss;
    __syncthreads();
    const int base = (tid & 192) | (r ? 0 : 0);
    // partials for this row live at indices (tid&192) is wrong grouping; recompute:
    // within this 64-thread group (one tile), partial index = r*?  Actually:
    // group = tid>>6 (0..3), each group handles one (t) tile? No: gid mapping
    // interleaves ks/hi within 64 lanes; partials for row r of this group are
    // at group*64 + {ks,hi} lanes where (lane&31)==r, i.e. offsets r and r+32,
    // for each of ks 0..3 -> need sum over lanes {ks*64... } -- but lanes span
    // only 64 per group with all 4 ks values: (gid>>6)&3 = ks means ks is
    // PER-GROUP uniform. So one group = one (t,ks): 64 lanes = 32 rows x 2 hi.
    // Row partial pair: group*64 + r (hi=0) and group*64 + 32 + r (hi=1).
    // Four groups in the block = 4 ks of the SAME tile t? (gid>>8)&511 = t
    // changes every 4 groups -> yes, block = 1 tile x 4 ks. Good:
    float tot = ssl[0 * 64 + r] + ssl[0 * 64 + 32 + r]
              + ssl[1 * 64 + r] + ssl[1 * 64 + 32 + r]
              + ssl[2 * 64 + r] + ssl[2 * 64 + 32 + r]
              + ssl[3 * 64 + r] + ssl[3 * 64 + 32 + r];
    const float rn = 1.0f / fmaxf(sqrtf(tot), EPS);
    if (ks == 0 && hi == 0) knr[h * MMEM + row] = rn;

    uint4 o;
    o.x = (unsigned)f2bf(v0.x * rn) | ((unsigned)f2bf(v0.y * rn) << 16);
    o.y = (unsigned)f2bf(v0.z * rn) | ((unsigned)f2bf(v0.w * rn) << 16);
    o.z = (unsigned)f2bf(v1.x * rn) | ((unsigned)f2bf(v1.y * rn) << 16);
    o.w = (unsigned)f2bf(v1.z * rn) | ((unsigned)f2bf(v1.w * rn) << 16);
    *(uint4*)(kbf + (size_t)gid * 8) = o;
}

// ---------------------------------------------------------------------------
// Shared scan helpers
// ---------------------------------------------------------------------------
#define MAX16(ACC)                                                            \
    fmaxf(fmaxf(fmaxf(fmaxf(ACC[0],ACC[1]),fmaxf(ACC[2],ACC[3])),             \
                fmaxf(fmaxf(ACC[4],ACC[5]),fmaxf(ACC[6],ACC[7]))),            \
          fmaxf(fmaxf(fmaxf(ACC[8],ACC[9]),fmaxf(ACC[10],ACC[11])),           \
                fmaxf(fmaxf(ACC[12],ACC[13]),fmaxf(ACC[14],ACC[15]))))

__device__ inline void ins8(float (&tv)[8], float v) {
#pragma unroll
    for (int j = 0; j < 8; ++j) {
        float h_ = fmaxf(tv[j], v);
        float l_ = fminf(tv[j], v);
        tv[j] = h_;
        v = l_;
    }
}

__device__ inline void ins8u64(unsigned long long (&tv)[8], unsigned long long v) {
#pragma unroll
    for (int j = 0; j < 8; ++j) {
        unsigned long long h_ = tv[j] > v ? tv[j] : v;
        unsigned long long l_ = tv[j] > v ? v : tv[j];
        tv[j] = h_;
        v = l_;
    }
}

__device__ inline bf16x8 pack8f(float4 a, float4 b) {
    bf16x8 f;
    f[0] = (short)f2bf(a.x); f[1] = (short)f2bf(a.y);
    f[2] = (short)f2bf(a.z); f[3] = (short)f2bf(a.w);
    f[4] = (short)f2bf(b.x); f[5] = (short)f2bf(b.y);
    f[6] = (short)f2bf(b.z); f[7] = (short)f2bf(b.w);
    return f;
}

#define MFMA8(AF0, AF1, AF2, AF3)                                             \
    f32x16 accA = {0,0,0,0,0,0,0,0,0,0,0,0,0,0,0,0};                         \
    f32x16 accB = {0,0,0,0,0,0,0,0,0,0,0,0,0,0,0,0};                         \
    accA = __builtin_amdgcn_mfma_f32_32x32x16_bf16(AF0, qA[0], accA, 0, 0, 0);\
    accB = __builtin_amdgcn_mfma_f32_32x32x16_bf16(AF0, qB[0], accB, 0, 0, 0);\
    accA = __builtin_amdgcn_mfma_f32_32x32x16_bf16(AF1, qA[1], accA, 0, 0, 0);\
    accB = __builtin_amdgcn_mfma_f32_32x32x16_bf16(AF1, qB[1], accB, 0, 0, 0);\
    accA = __builtin_amdgcn_mfma_f32_32x32x16_bf16(AF2, qA[2], accA, 0, 0, 0);\
    accB = __builtin_amdgcn_mfma_f32_32x32x16_bf16(AF2, qB[2], accB, 0, 0, 0);\
    accA = __builtin_amdgcn_mfma_f32_32x32x16_bf16(AF3, qA[3], accA, 0, 0, 0);\
    accB = __builtin_amdgcn_mfma_f32_32x32x16_bf16(AF3, qB[3], accB, 0, 0, 0);

#define LOADQ()                                                               \
    bf16x8 qA[4], qB[4];                                                      \
    {                                                                         \
        const int b0 = n0 >> 9, s0 = n0 & 511;                                \
        const int b1 = n1 >> 9, s1 = n1 & 511;                                \
        const float* qp0 = query + ((((size_t)b0 * NHEADS + h) * SEQ + s0) << 6); \
        const float* qp1 = query + ((((size_t)b1 * NHEADS + h) * SEQ + s1) << 6); \
        _Pragma("unroll")                                                     \
        for (int ks = 0; ks < 4; ++ks) {                                      \
            const int d0 = ks * 16 + hi * 8;                                  \
            qA[ks] = pack8f(*(const float4*)(qp0 + d0), *(const float4*)(qp0 + d0 + 4)); \
            qB[ks] = pack8f(*(const float4*)(qp1 + d0), *(const float4*)(qp1 + d0 + 4)); \
        }                                                                     \
    }

// ---------------------------------------------------------------------------
// Kernel 2 (scanA): MFMA pass 1. One wave/block, 64 queries x 1024 mems
// (partition of 32 tiles). Selection = ONE running fmax per (query, half):
// writes the group max (a real similarity value) to pmax[q][p*2+hi].
// D-layout: col=lane&31 (query), row=(reg&3)+8*(reg>>2)+4*(lane>>5) (mem).
// ---------------------------------------------------------------------------
__global__ __launch_bounds__(64, 4)
void scanA_kernel(const float* __restrict__ query,
                  const unsigned short* __restrict__ kbf,
                  float* __restrict__ pmax) {
    const int lane = threadIdx.x;
    int bid = blockIdx.x;
    const int p  = bid & 15;  bid >>= 4;
    const int qg = bid & 15;  bid >>= 4;
    const int h  = bid;
    const int col = lane & 31;
    const int hi  = lane >> 5;
    const int n0  = qg * 64 + col;
    const int n1  = n0 + 32;

    LOADQ()

    float gA = -1e30f, gB = -1e30f;

    const unsigned char* ptr = (const unsigned char*)kbf
        + ((size_t)h * 512 + (size_t)p * NT) * 4096 + (size_t)lane * 16;

    bf16x8 aX0, aX1, aX2, aX3, aY0, aY1, aY2, aY3;
    aX0 = *(const bf16x8*)(ptr);
    aX1 = *(const bf16x8*)(ptr + 1024);
    aX2 = *(const bf16x8*)(ptr + 2048);
    aX3 = *(const bf16x8*)(ptr + 3072);

#pragma unroll 1
    for (int t = 0; t < NT; t += 2) {
        {
            const unsigned char* pn = ptr + (size_t)(t + 1) * 4096;
            aY0 = *(const bf16x8*)(pn);
            aY1 = *(const bf16x8*)(pn + 1024);
            aY2 = *(const bf16x8*)(pn + 2048);
            aY3 = *(const bf16x8*)(pn + 3072);
        }
        {
            MFMA8(aX0, aX1, aX2, aX3)
            gA = fmaxf(gA, MAX16(accA));
            gB = fmaxf(gB, MAX16(accB));
        }
        if (t + 2 < NT) {
            const unsigned char* p2 = ptr + (size_t)(t + 2) * 4096;
            aX0 = *(const bf16x8*)(p2);
            aX1 = *(const bf16x8*)(p2 + 1024);
            aX2 = *(const bf16x8*)(p2 + 2048);
            aX3 = *(const bf16x8*)(p2 + 3072);
        }
        {
            MFMA8(aY0, aY1, aY2, aY3)
            gA = fmaxf(gA, MAX16(accA));
            gB = fmaxf(gB, MAX16(accB));
        }
    }

    const int g = p * 2 + hi;
    pmax[(((size_t)h * NQ + n0) << 5) + g] = gA;
    pmax[(((size_t)h * NQ + n1) << 5) + g] = gB;
}

// ---------------------------------------------------------------------------
// Kernel 3 (taured): per query, exact 8th-largest of its 32 group maxes.
// Each group max is a real value of that query, so tau_q <= v8: superset-safe.
// ---------------------------------------------------------------------------
__global__ __launch_bounds__(256)
void taured_kernel(const float* __restrict__ pmax,
                   float* __restrict__ tauv) {
    const int gid = blockIdx.x * 256 + threadIdx.x;   // query id h*NQ+n
    float tv[8];
#pragma unroll
    for (int j = 0; j < 8; ++j) tv[j] = -1e30f;
#pragma unroll
    for (int k = 0; k < NGRP; ++k) ins8(tv, pmax[((size_t)gid << 5) + k]);
    tauv[gid] = tv[7];
}

// ---------------------------------------------------------------------------
// Kernel 4 (scanB): MFMA pass 2, emit mem indices with bf16-score >=
// tau_q - margin_q (margin = 2*2^-8*||q|| + 0.01 covers bf16 rounding of
// both operands -> emitted set provably contains the fp32 top-8).
// Emission via per-lane 16-bit trigger mask + ffs decode (rare body).
// ---------------------------------------------------------------------------
__global__ __launch_bounds__(64, 4)
void scanB_kernel(const float* __restrict__ query,
                  const unsigned short* __restrict__ kbf,
                  const float* __restrict__ tauv,
                  unsigned* __restrict__ pcand,
                  unsigned* __restrict__ pcnt) {
    const int lane = threadIdx.x;
    int bid = blockIdx.x;
    const int p  = bid & 15;  bid >>= 4;
    const int qg = bid & 15;  bid >>= 4;
    const int h  = bid;
    const int col = lane & 31;
    const int hi  = lane >> 5;
    const int n0  = qg * 64 + col;
    const int n1  = n0 + 32;

    bf16x8 qA[4], qB[4];
    float ssA = 0.f, ssB = 0.f;
    {
        const int b0 = n0 >> 9, s0 = n0 & 511;
        const int b1 = n1 >> 9, s1 = n1 & 511;
        const float* qp0 = query + ((((size_t)b0 * NHEADS + h) * SEQ + s0) << 6);
        const float* qp1 = query + ((((size_t)b1 * NHEADS + h) * SEQ + s1) << 6);
#pragma unroll
        for (int ks = 0; ks < 4; ++ks) {
            const int d0 = ks * 16 + hi * 8;
            float4 a0 = *(const float4*)(qp0 + d0), b0v = *(const float4*)(qp0 + d0 + 4);
            float4 a1 = *(const float4*)(qp1 + d0), b1v = *(const float4*)(qp1 + d0 + 4);
            ssA += SS(a0) + SS(b0v);
            ssB += SS(a1) + SS(b1v);
            qA[ks] = pack8f(a0, b0v);
            qB[ks] = pack8f(a1, b1v);
        }
    }
    ssA += __shfl_xor(ssA, 32);   // other half's dims (same query)
    ssB += __shfl_xor(ssB, 32);
    const float tA = tauv[h * NQ + n0] - (sqrtf(ssA) * 0.0078125f + 0.01f);
    const float tB = tauv[h * NQ + n1] - (sqrtf(ssB) * 0.0078125f + 0.01f);

    const unsigned char* ptr = (const unsigned char*)kbf
        + ((size_t)h * 512 + (size_t)p * NT) * 4096 + (size_t)lane * 16;

    unsigned cA = 0, cB = 0;
    const size_t chA = (((size_t)h * NQ + n0) << 5) + p * 2 + hi;
    const size_t chB = (((size_t)h * NQ + n1) << 5) + p * 2 + hi;
    unsigned* mApt = pcand + chA * CMAX;
    unsigned* mBpt = pcand + chB * CMAX;

#define EMITM(ACC, TAU, C, LST, MBV) do {                                     \
        unsigned _msk = 0;                                                    \
        _Pragma("unroll")                                                     \
        for (int _r = 0; _r < 16; ++_r)                                       \
            _msk |= (ACC[_r] >= (TAU)) ? (1u << _r) : 0u;                     \
        if (_msk) {                                                           \
            do {                                                              \
                int _r = __ffs(_msk) - 1;                                     \
                unsigned _idx = (unsigned)((MBV) + (_r & 3) + 8 * (_r >> 2)); \
                if ((C) < CMAX) (LST)[C] = _idx;                              \
                ++(C);                                                        \
                _msk &= _msk - 1;                                             \
            } while (_msk);                                                   \
        }                                                                     \
    } while (0)

    bf16x8 aX0, aX1, aX2, aX3, aY0, aY1, aY2, aY3;
    aX0 = *(const bf16x8*)(ptr);
    aX1 = *(const bf16x8*)(ptr + 1024);
    aX2 = *(const bf16x8*)(ptr + 2048);
    aX3 = *(const bf16x8*)(ptr + 3072);

#pragma unroll 1
    for (int t = 0; t < NT; t += 2) {
        {
            const unsigned char* pn = ptr + (size_t)(t + 1) * 4096;
            aY0 = *(const bf16x8*)(pn);
            aY1 = *(const bf16x8*)(pn + 1024);
            aY2 = *(const bf16x8*)(pn + 2048);
            aY3 = *(const bf16x8*)(pn + 3072);
        }
        {
            MFMA8(aX0, aX1, aX2, aX3)
            const int mbv = p * 1024 + t * 32 + 4 * hi;
            EMITM(accA, tA, cA, mApt, mbv);
            EMITM(accB, tB, cB, mBpt, mbv);
        }
        if (t + 2 < NT) {
            const unsigned char* p2 = ptr + (size_t)(t + 2) * 4096;
            aX0 = *(const bf16x8*)(p2);
            aX1 = *(const bf16x8*)(p2 + 1024);
            aX2 = *(const bf16x8*)(p2 + 2048);
            aX3 = *(const bf16x8*)(p2 + 3072);
        }
        {
            MFMA8(aY0, aY1, aY2, aY3)
            const int mbv = p * 1024 + (t + 1) * 32 + 4 * hi;
            EMITM(accA, tA, cA, mApt, mbv);
            EMITM(accB, tB, cB, mBpt, mbv);
        }
    }
    pcnt[chA] = cA;
    pcnt[chB] = cB;
#undef EMITM
}

// ---------------------------------------------------------------------------
// Kernel 5 (rescore_merge): one wave per query. Lane d4=lane&15 holds the
// query float4; candidate dot = per-lane partial + 4 shfl_xor. Exact top-8
// via packed u64 keys (monotone(score)<<32 | ~idx): order = (score desc,
// idx asc), branchless ins8u64, bit-exact score recovery. V-gather: lane i
// owns output element i. Overflow -> exact full-memory loop.
// ---------------------------------------------------------------------------
__global__ __launch_bounds__(64, 8)
void rescore_merge_kernel(const float* __restrict__ query,
                          const float* __restrict__ kmem,
                          const float* __restrict__ knr,
                          const unsigned* __restrict__ pcand,
                          const unsigned* __restrict__ pcnt,
                          const float* __restrict__ vmem,
                          const float* __restrict__ outputs,
                          const float* __restrict__ gate,
                          float* __restrict__ out) {
    __shared__ unsigned cands[NGRP * CMAX];
    const int gid = blockIdx.x;            // query id
    const int h = gid >> 10;
    const int n = gid & 1023;
    const int b = n >> 9;
    const int s = n & 511;
    const int lane = threadIdx.x;
    const int d4 = lane & 15;
    const int d5 = lane & 31;

    const float* qbase = query + ((((size_t)b * NHEADS + h) * SEQ + s) << 6);
    const float4 q4 = ((const float4*)qbase)[d4];
    float ssp = SS(q4);
    ssp += __shfl_xor(ssp, 1);
    ssp += __shfl_xor(ssp, 2);
    ssp += __shfl_xor(ssp, 4);
    ssp += __shfl_xor(ssp, 8);     // full ||q||^2 within each 16-lane group
    const float qs = 1.0f / (fmaxf(sqrtf(ssp), EPS) * 8.0f);

    // compact the 32 candidate lists into LDS (32-lane shfl prefix scan)
    const unsigned cg = pcnt[((size_t)gid << 5) + d5];
    const bool anyovf = (__ballot(cg > CMAX) != 0ULL);
    unsigned inc = cg;
#pragma unroll
    for (int d = 1; d < 32; d <<= 1) {
        unsigned t = __shfl_up(inc, d, 32);
        if (d5 >= d) inc += t;
    }
    const unsigned ct = __shfl(inc, 31, 32);
    const unsigned excl = inc - cg;
    if (lane < 32) {
        const unsigned* lp = pcand + (((size_t)gid << 5) + lane) * CMAX;
        const unsigned cc = cg > CMAX ? CMAX : cg;
        for (unsigned c = 0; c < cc; ++c) cands[excl + c] = lp[c];
    }
    __syncthreads();

    const float* kb = kmem + ((size_t)h << 20);
    const float* nb = knr + h * MMEM;

    unsigned long long top[8];
#pragma unroll
    for (int j = 0; j < 8; ++j) top[j] = 0ULL;

#define SCORE_KEY(IDX) ({                                                     \
        float4 kv = ((const float4*)(kb + ((size_t)(IDX) << 6)))[d4];         \
        float d = q4.x*kv.x + q4.y*kv.y + q4.z*kv.z + q4.w*kv.w;              \
        d += __shfl_xor(d, 1);                                                \
        d += __shfl_xor(d, 2);                                                \
        d += __shfl_xor(d, 4);                                                \
        d += __shfl_xor(d, 8);                                                \
        const float sc = d * qs * nb[IDX];                                    \
        unsigned su = __builtin_bit_cast(unsigned, sc);                       \
        unsigned ms = su ^ ((su >> 31) ? 0xFFFFFFFFu : 0x80000000u);          \
        ((unsigned long long)ms << 32) | (0xFFFFFFFFu - (unsigned)(IDX));     \
    })

    if (!anyovf) {
#pragma unroll 1
        for (unsigned c = 0; c < ct; ++c) {
            const unsigned idx = cands[c];
            ins8u64(top, SCORE_KEY(idx));
        }
    } else {
        // exact fallback: all memories (practically never taken)
#pragma unroll 1
        for (int m = 0; m < MMEM; ++m) ins8u64(top, SCORE_KEY(m));
    }
#undef SCORE_KEY

    // V-gather + gate blend: lane owns output element `lane`
    float acc = 0.0f;
    const float* vb = vmem + ((size_t)h << 20);
#pragma unroll
    for (int j = 0; j < 8; ++j) {
        const unsigned long long key = top[j];
        const unsigned idx = 0xFFFFFFFFu - (unsigned)(key & 0xFFFFFFFFu);
        const unsigned ms = (unsigned)(key >> 32);
        const unsigned su = ms ^ ((ms >> 31) ? 0x80000000u : 0xFFFFFFFFu);
        const float sc = __builtin_bit_cast(float, su);
        acc = fmaf(sc, vb[((size_t)idx << 6) + lane], acc);
    }

    const float gg = 1.0f / (1.0f + expf(-gate[h]));
    const size_t off = ((((size_t)b * NHEADS + h) * SEQ + s) << 6) + lane;
    out[off] = gg * acc + (1.0f - gg) * outputs[off];
}

// ---------------------------------------------------------------------------
// Fallback path (ws too small): fp32 scan + merge (previous rounds').
// ---------------------------------------------------------------------------
__global__ void knorm_kernel(const float* __restrict__ kmem,
                             float* __restrict__ knr) {
    int gid = blockIdx.x * 256 + threadIdx.x;
    int mem = gid >> 4;
    int d4  = gid & 15;
    float4 kv = reinterpret_cast<const float4*>(kmem)[(size_t)mem * 16 + d4];
    float ss = SS(kv);
    ss += __shfl_xor(ss, 1);
    ss += __shfl_xor(ss, 2);
    ss += __shfl_xor(ss, 4);
    ss += __shfl_xor(ss, 8);
    if (d4 == 0) knr[mem] = 1.0f / fmaxf(sqrtf(ss), EPS);
}

__global__ __launch_bounds__(64, 4)
void scan_kernel(const float* __restrict__ query,
                 const float* __restrict__ kmem,
                 const float* __restrict__ knr,
                 float* __restrict__ pscore,
                 int* __restrict__ pidx,
                 int P, int CH) {
    const int lane = threadIdx.x & 63;
    int bid = blockIdx.x;
    const int p  = bid % P;  bid /= P;
    const int qb = bid & 15; bid >>= 4;
    const int h  = bid;
    const int n  = qb * 64 + lane;
    const int b  = n >> 9;
    const int s  = n & 511;

    const float4* qp = reinterpret_cast<const float4*>(
        query + (((size_t)b * NHEADS + h) * SEQ + s) * HD);
    float q[HD];
    float ss = 0.0f;
#pragma unroll
    for (int i = 0; i < 16; ++i) {
        float4 v = qp[i];
        q[4*i+0] = v.x; q[4*i+1] = v.y; q[4*i+2] = v.z; q[4*i+3] = v.w;
        ss += SS(v);
    }
    const float rq = 1.0f / (fmaxf(sqrtf(ss), EPS) * 8.0f);
#pragma unroll
    for (int i = 0; i < HD; ++i) q[i] *= rq;

    float tv[8]; int ti[8];
#pragma unroll
    for (int j = 0; j < 8; ++j) { tv[j] = -INFINITY; ti[j] = 0; }

    const int m0 = p * CH;
    const float4* kp = reinterpret_cast<const float4*>(
        kmem + ((size_t)h * MMEM + m0) * HD);
    const float* knrp = knr + h * MMEM + m0;

    for (int mm = 0; mm < CH; ++mm) {
        float d0 = 0.f, d1 = 0.f, d2 = 0.f, d3 = 0.f;
#pragma unroll
        for (int i = 0; i < 16; ++i) {
            float4 kv = kp[(size_t)mm * 16 + i];
            d0 = fmaf(q[4*i+0], kv.x, d0);
            d1 = fmaf(q[4*i+1], kv.y, d1);
            d2 = fmaf(q[4*i+2], kv.z, d2);
            d3 = fmaf(q[4*i+3], kv.w, d3);
        }
        const float sim = ((d0 + d1) + (d2 + d3)) * knrp[mm];
        if (sim > tv[7]) {
            tv[7] = sim; ti[7] = m0 + mm;
#pragma unroll
            for (int j = 7; j > 0; --j) {
                if (tv[j] > tv[j-1]) {
                    float tf = tv[j]; tv[j] = tv[j-1]; tv[j-1] = tf;
                    int   tu = ti[j]; ti[j] = ti[j-1]; ti[j-1] = tu;
                }
            }
        }
    }

    const size_t base = (((size_t)h * NQ + n) * P + p) * 8;
#pragma unroll
    for (int j = 0; j < 8; ++j) { pscore[base+j] = tv[j]; pidx[base+j] = ti[j]; }
}

__global__ void merge_kernel(const float* __restrict__ pscore,
                             const int* __restrict__ pidx,
                             const float* __restrict__ vmem,
                             const float* __restrict__ outputs,
                             const float* __restrict__ gate,
                             float* __restrict__ out, int P) {
    const int t = blockIdx.x * 256 + threadIdx.x;
    const int h = t >> 10;
    const int n = t & 1023;
    const int b = n >> 9;
    const int s = n & 511;

    float tv[8]; int ti[8];
    const size_t base = ((size_t)h * NQ + n) * P * 8;
#pragma unroll
    for (int j = 0; j < 8; ++j) { tv[j] = pscore[base + j]; ti[j] = pidx[base + j]; }
    const int total = P * 8;
    for (int c = 8; c < total; ++c) {
        const float v = pscore[base + c];
        if (v > tv[7]) {
            tv[7] = v; ti[7] = pidx[base + c];
#pragma unroll
            for (int j = 7; j > 0; --j) {
                if (tv[j] > tv[j-1]) {
                    float tf = tv[j]; tv[j] = tv[j-1]; tv[j-1] = tf;
                    int   tu = ti[j]; ti[j] = ti[j-1]; ti[j-1] = tu;
                }
            }
        }
    }

    float4 acc[16];
#pragma unroll
    for (int i = 0; i < 16; ++i) acc[i] = make_float4(0.f, 0.f, 0.f, 0.f);
#pragma unroll
    for (int j = 0; j < 8; ++j) {
        const float4* vp = reinterpret_cast<const float4*>(
            vmem + ((size_t)h * MMEM + ti[j]) * HD);
        const float sc = tv[j];
#pragma unroll
        for (int i = 0; i < 16; ++i) {
            float4 v = vp[i];
            acc[i].x = fmaf(sc, v.x, acc[i].x);
            acc[i].y = fmaf(sc, v.y, acc[i].y);
            acc[i].z = fmaf(sc, v.z, acc[i].z);
            acc[i].w = fmaf(sc, v.w, acc[i].w);
        }
    }

    const float g  = 1.0f / (1.0f + expf(-gate[h]));
    const float og = 1.0f - g;
    const size_t off = (((size_t)b * NHEADS + h) * SEQ + s) * HD;
    const float4* op = reinterpret_cast<const float4*>(outputs + off);
    float4* dst = reinterpret_cast<float4*>(out + off);
#pragma unroll
    for (int i = 0; i < 16; ++i) {
        float4 o = op[i];
        float4 r;
        r.x = g * acc[i].x + og * o.x;
        r.y = g * acc[i].y + og * o.y;
        r.z = g * acc[i].z + og * o.z;
        r.w = g * acc[i].w + og * o.w;
        dst[i] = r;
    }
}

// ---------------------------------------------------------------------------
extern "C" void kernel_launch(void* const* d_in, const int* in_sizes, int n_in,
                              void* d_out, int out_size, void* d_ws, size_t ws_size,
                              hipStream_t stream) {
    const float* query   = (const float*)d_in[1];
    const float* outputs = (const float*)d_in[4];
    const float* gate    = (const float*)d_in[5];
    const float* kmem    = (const float*)d_in[6];
    const float* vmem    = (const float*)d_in[7];
    float* out = (float*)d_out;

    const size_t NQTOT    = (size_t)NHEADS * NQ;                 // 16384 queries
    const size_t sz_knr   = (size_t)NHEADS * MMEM * 4;           //  1.0 MB
    const size_t sz_kbf   = (size_t)NHEADS * MMEM * HD * 2;      // 33.5 MB
    const size_t sz_pmax  = NQTOT * NGRP * 4;                    //  2.1 MB
    const size_t sz_tauv  = NQTOT * 4;                           //  0.07 MB
    const size_t sz_pcand = NQTOT * NGRP * CMAX * 4;             // 16.8 MB
    const size_t sz_pcnt  = NQTOT * NGRP * 4;                    //  2.1 MB
    const size_t need = sz_knr + sz_kbf + sz_pmax + sz_tauv + sz_pcand + sz_pcnt;

    if (ws_size >= need) {
        char* w = (char*)d_ws;
        float*          knr   = (float*)w;          w += sz_knr;
        unsigned short* kbf   = (unsigned short*)w; w += sz_kbf;
        float*          pmax  = (float*)w;          w += sz_pmax;
        float*          tauv  = (float*)w;          w += sz_tauv;
        unsigned*       pcand = (unsigned*)w;       w += sz_pcand;
        unsigned*       pcnt  = (unsigned*)w;

        kprep_kernel<<<(NHEADS * 512 * 4 * 64) / 256, 256, 0, stream>>>(kmem, knr, kbf);
        scanA_kernel<<<NHEADS * 16 * NPART, 64, 0, stream>>>(query, kbf, pmax);
        taured_kernel<<<(int)(NQTOT / 256), 256, 0, stream>>>(pmax, tauv);
        scanB_kernel<<<NHEADS * 16 * NPART, 64, 0, stream>>>(query, kbf, tauv, pcand, pcnt);
        rescore_merge_kernel<<<(int)NQTOT, 64, 0, stream>>>(
            query, kmem, knr, pcand, pcnt, vmem, outputs, gate, out);
    } else {
        int P = 16;
        while (P > 4 &&
               (size_t)NHEADS * MMEM * 4 + (size_t)NHEADS * NQ * (size_t)P * 64 > ws_size)
            P >>= 1;
        const int CH = MMEM / P;

        float* knr    = (float*)d_ws;
        float* pscore = knr + (size_t)NHEADS * MMEM;
        int*   pidx   = (int*)(pscore + (size_t)NHEADS * NQ * (size_t)P * 8);

        knorm_kernel<<<(NHEADS * MMEM * 16) / 256, 256, 0, stream>>>(kmem, knr);
        scan_kernel<<<NHEADS * 16 * P, 64, 0, stream>>>(
            query, kmem, knr, pscore, pidx, P, CH);
        merge_kernel<<<(NHEADS * NQ) / 256, 256, 0, stream>>>(
            pscore, pidx, vmem, outputs, gate, out, P);
    }
}